// Round 16
// baseline (811.983 us; speedup 1.0000x reference)
//
#include <hip/hip_runtime.h>
#include <hip/hip_bf16.h>
#include <type_traits>

#define NN 50000
#define NP 50048   // NN padded to 128*391
#define EE 800000
#define TT 3
#define ED 64
#define NS 23
#define MD 87
#define HH 200
#define NMOL 2048
#define RD 256

#define SP 216     // LDS hi-plane stride (shorts)
#define NPB2 512   // colstats partial blocks
#define SNB ((NN + 255) / 256)  // 196 scan blocks

typedef __attribute__((ext_vector_type(8))) short short8b;
typedef __attribute__((ext_vector_type(4))) short short4b;
typedef __attribute__((ext_vector_type(4))) float f32x4;

// ---- bf16 helpers ----
__device__ __forceinline__ unsigned short f2bf(float f) {
  unsigned u = __float_as_uint(f);
  return (unsigned short)((u + 0x7fffu + ((u >> 16) & 1u)) >> 16);
}
__device__ __forceinline__ float ubf2f(unsigned short h) {
  return __uint_as_float(((unsigned)h) << 16);
}
// interleaved pair in one u32: low16 = hi-bf16, high16 = lo-bf16 (fp32-equivalent)
__device__ __forceinline__ float bfp2f(unsigned p) {
  return __uint_as_float(p << 16) + __uint_as_float(p & 0xffff0000u);
}
__device__ __forceinline__ unsigned packsplit(float v) {
  unsigned short h = f2bf(v);
  unsigned short l = f2bf(v - ubf2f(h));
  return (unsigned)h | ((unsigned)l << 16);
}

// ---------------- weight prep: fp32 [T][K][N] -> bf16 hi/lo planes [T][Npad][Kpad] ----
struct WD { const float* src; short* dh; short* dl; int K, N, Kpad, Npad, T; };
struct WDs { WD d[7]; };

__global__ __launch_bounds__(256) void wprep_kernel(WDs W) {
  WD w = W.d[blockIdx.y];
  int per = w.Npad * w.Kpad;
  int total = w.T * per;
  for (int idx = blockIdx.x * 256 + threadIdx.x; idx < total; idx += gridDim.x * 256) {
    int t = idx / per;
    int r = idx - t * per;
    int n = r / w.Kpad;
    int k = r - n * w.Kpad;
    float v = 0.f;
    if (k < w.K && n < w.N) v = w.src[((size_t)t * w.K + k) * w.N + n];
    unsigned short h = f2bf(v);
    unsigned short l = f2bf(v - ubf2f(h));
    w.dh[idx] = (short)h;
    w.dl[idx] = (short)l;
  }
}

// ---------------- embedding -> x slice 0 (pair + hi plane) ----------------
__global__ __launch_bounds__(256) void emb_kernel(const int* __restrict__ z,
                                                  const float* __restrict__ emb,
                                                  unsigned* __restrict__ xp,
                                                  short* __restrict__ xq) {
  int idx = blockIdx.x * 256 + threadIdx.x;
  if (idx >= NN * ED) return;
  int i = idx >> 6, d = idx & 63;
  unsigned pk = packsplit(emb[z[i] * ED + d]);
  xp[(size_t)i * RD + d] = pk;
  xq[(size_t)i * RD + d] = (short)(pk & 0xffffu);
}

// ---------------- CSR build ----------------
__global__ __launch_bounds__(256) void hist_kernel(const int* __restrict__ src,
                                                   int* __restrict__ deg) {
  int e = blockIdx.x * 256 + threadIdx.x;
  if (e < EE) atomicAdd(&deg[src[e]], 1);
}

// 3-stage parallel exclusive scan of deg[0..NN)
__global__ __launch_bounds__(256) void scanA_kernel(const int* __restrict__ deg,
                                                    int* __restrict__ Psum) {
  int i = blockIdx.x * 256 + threadIdx.x;
  int v = (i < NN) ? deg[i] : 0;
#pragma unroll
  for (int off = 32; off > 0; off >>= 1) v += __shfl_down(v, off, 64);
  __shared__ int ws[4];
  if ((threadIdx.x & 63) == 0) ws[threadIdx.x >> 6] = v;
  __syncthreads();
  if (threadIdx.x == 0) Psum[blockIdx.x] = ws[0] + ws[1] + ws[2] + ws[3];
}

__global__ __launch_bounds__(256) void scanB_kernel(const int* __restrict__ Psum,
                                                    int* __restrict__ Poff) {
  __shared__ int sh[256];
  int t = threadIdx.x;
  int v = (t < SNB) ? Psum[t] : 0;
  sh[t] = v;
  __syncthreads();
  for (int off = 1; off < 256; off <<= 1) {
    int u = (t >= off) ? sh[t - off] : 0;
    __syncthreads();
    sh[t] += u;
    __syncthreads();
  }
  if (t < SNB) Poff[t] = sh[t] - v;  // exclusive
}

__global__ __launch_bounds__(256) void scanC_kernel(const int* __restrict__ deg,
                                                    const int* __restrict__ Poff,
                                                    int* __restrict__ offs,
                                                    int* __restrict__ cursor) {
  __shared__ int sh[256];
  int t = threadIdx.x;
  int i = blockIdx.x * 256 + t;
  int v = (i < NN) ? deg[i] : 0;
  sh[t] = v;
  __syncthreads();
  for (int off = 1; off < 256; off <<= 1) {
    int u = (t >= off) ? sh[t - off] : 0;
    __syncthreads();
    sh[t] += u;
    __syncthreads();
  }
  int excl = Poff[blockIdx.x] + sh[t] - v;
  if (i < NN) {
    offs[i] = excl;
    cursor[i] = excl;
    if (i == NN - 1) offs[NN] = excl + v;
  }
}

__global__ __launch_bounds__(256) void scatter_kernel(const int* __restrict__ src,
                                                      const int* __restrict__ snk,
                                                      const float* __restrict__ dist,
                                                      int* __restrict__ cursor,
                                                      int* __restrict__ ssink,
                                                      float* __restrict__ sdist) {
  int e = blockIdx.x * 256 + threadIdx.x;
  if (e >= EE) return;
  int p = atomicAdd(&cursor[src[e]], 1);
  ssink[p] = snk[e];
  sdist[p] = dist[e];
}

// ---------------- message gather: one wave per node, hi-plane reads ----------
__global__ __launch_bounds__(256) void gather_kernel(const int* __restrict__ offs,
                                                     const int* __restrict__ ssink,
                                                     const float* __restrict__ sdist,
                                                     const short* __restrict__ xq,
                                                     int toff, unsigned* __restrict__ m) {
  int node = blockIdx.x * 4 + (threadIdx.x >> 6);
  int lane = threadIdx.x & 63;
  if (node >= NN) return;
  float shift = (float)(0.8 + 0.1 * (double)lane);
  int e0 = offs[node], e1 = offs[node + 1];
  float ax0 = 0.f, ax1 = 0.f, ar0 = 0.f, ar1 = 0.f;
  int j = e0;
  for (; j + 4 <= e1; j += 4) {
    int s0 = ssink[j], s1 = ssink[j + 1], s2 = ssink[j + 2], s3 = ssink[j + 3];
    float d0 = sdist[j], d1 = sdist[j + 1], d2 = sdist[j + 2], d3 = sdist[j + 3];
    float x0 = ubf2f((unsigned short)xq[(size_t)s0 * RD + toff + lane]);
    float x1 = ubf2f((unsigned short)xq[(size_t)s1 * RD + toff + lane]);
    float x2 = ubf2f((unsigned short)xq[(size_t)s2 * RD + toff + lane]);
    float x3 = ubf2f((unsigned short)xq[(size_t)s3 * RD + toff + lane]);
    ax0 += x0 + x2;
    ax1 += x1 + x3;
    if (lane < NS) {
      float u0 = d0 - shift, u1 = d1 - shift, u2 = d2 - shift, u3 = d3 - shift;
      ar0 += __expf(-u0 * u0) + __expf(-u2 * u2);
      ar1 += __expf(-u1 * u1) + __expf(-u3 * u3);
    }
  }
  for (; j < e1; j++) {
    int s = ssink[j];
    float d = sdist[j];
    ax0 += ubf2f((unsigned short)xq[(size_t)s * RD + toff + lane]);
    if (lane < NS) {
      float u = d - shift;
      ar0 += __expf(-u * u);
    }
  }
  float accx = ax0 + ax1, accr = ar0 + ar1;
  if (lane < NS) m[node * 96 + lane] = packsplit(accr);
  m[node * 96 + NS + lane] = packsplit(accx);
}

// ---------------- batchnorm stats: stage 1 (vectorized, 512 blocks) ----------
template <int LD>
__global__ __launch_bounds__(256) void colstats2_kernel(const unsigned* __restrict__ X,
                                                        float* __restrict__ P) {
  constexpr int CG = LD / 4;
  constexpr int RPB = 256 / CG;
  const int t = threadIdx.x;
  const int cg = t % CG, rin = t / CG;
  float s0 = 0, s1 = 0, s2 = 0, s3 = 0, q0 = 0, q1 = 0, q2 = 0, q3 = 0;
  if (rin < RPB) {
    for (int r = blockIdx.x * RPB + rin; r < NN; r += gridDim.x * RPB) {
      uint4 v = *(const uint4*)(X + (size_t)r * LD + cg * 4);
      float f0 = bfp2f(v.x), f1 = bfp2f(v.y), f2 = bfp2f(v.z), f3 = bfp2f(v.w);
      s0 += f0; q0 += f0 * f0;
      s1 += f1; q1 += f1 * f1;
      s2 += f2; q2 += f2 * f2;
      s3 += f3; q3 += f3 * f3;
    }
  }
  __shared__ float sh[256][8];
  sh[t][0] = s0; sh[t][1] = s1; sh[t][2] = s2; sh[t][3] = s3;
  sh[t][4] = q0; sh[t][5] = q1; sh[t][6] = q2; sh[t][7] = q3;
  __syncthreads();
  if (rin == 0) {
#pragma unroll
    for (int rr = 1; rr < RPB; rr++) {
      const float* o = sh[rr * CG + cg];
      s0 += o[0]; s1 += o[1]; s2 += o[2]; s3 += o[3];
      q0 += o[4]; q1 += o[5]; q2 += o[6]; q3 += o[7];
    }
    float* Pb = P + blockIdx.x * 512;
    Pb[cg * 4 + 0] = s0; Pb[cg * 4 + 1] = s1; Pb[cg * 4 + 2] = s2; Pb[cg * 4 + 3] = s3;
    Pb[256 + cg * 4 + 0] = q0; Pb[256 + cg * 4 + 1] = q1;
    Pb[256 + cg * 4 + 2] = q2; Pb[256 + cg * 4 + 3] = q3;
  }
}

// ---------------- batchnorm stats: stage 2 (one block per column) ------------
__global__ __launch_bounds__(256) void bnfinal2_kernel(const float* __restrict__ P, int nblk,
                                                       const float* __restrict__ g,
                                                       const float* __restrict__ b, int ncols,
                                                       float* __restrict__ na,
                                                       float* __restrict__ nb) {
  int c = blockIdx.x;
  int t = threadIdx.x;
  float s = 0.f, q = 0.f;
  for (int i = t; i < nblk; i += 256) {
    s += P[i * 512 + c];
    q += P[i * 512 + 256 + c];
  }
#pragma unroll
  for (int off = 32; off > 0; off >>= 1) {
    s += __shfl_down(s, off, 64);
    q += __shfl_down(q, off, 64);
  }
  __shared__ float ws[4], wq[4];
  if ((t & 63) == 0) { ws[t >> 6] = s; wq[t >> 6] = q; }
  __syncthreads();
  if (t == 0) {
    s = ws[0] + ws[1] + ws[2] + ws[3];
    q = wq[0] + wq[1] + wq[2] + wq[3];
    if (c < ncols) {
      float mean = s / (float)NN;
      float var = q / (float)NN - mean * mean;
      float a = g[c] * rsqrtf(var + 1e-5f);
      na[c] = a;
      nb[c] = b[c] - mean * a;
    } else {
      na[c] = 0.f;  // pad cols -> BN-applied value 0
      nb[c] = 0.f;
    }
  }
}

// ---------------- BN apply: pair -> pre-normalized bf16 hi plane only --------
template <int LD>
__global__ __launch_bounds__(256) void bnapply_kernel(const unsigned* __restrict__ Xp,
                                                      const float* __restrict__ na,
                                                      const float* __restrict__ nb,
                                                      short* __restrict__ Xh) {
  int idx = blockIdx.x * 256 + threadIdx.x;  // over NP * LD/4
  if (idx >= NP * (LD / 4)) return;
  int row = idx / (LD / 4);
  int cg = (idx - row * (LD / 4)) * 4;
  short4b h;
  if (row < NN) {
    uint4 v = *(const uint4*)(Xp + (size_t)row * LD + cg);
    unsigned arr[4] = {v.x, v.y, v.z, v.w};
#pragma unroll
    for (int e = 0; e < 4; e++) {
      float f = bfp2f(arr[e]) * na[cg + e] + nb[cg + e];
      h[e] = (short)f2bf(f);
    }
  } else {
    h = (short4b){0, 0, 0, 0};
  }
  *(short4b*)(Xh + (size_t)row * LD + cg) = h;
}

// ---------------- fused MLP kernel ----------------
// R16: 128-node tile, 1024 threads = 16 waves in 4(M) x 4(N); acc[2][4].
// R11/R14/R15 evidence: HW holds ~2 workgroups/CU regardless of LDS/VGPR
// headroom, so waves/CU scales with BLOCK SIZE -> 1024-thr blocks give
// 2 WG x 16 waves = 32 waves/CU (HW max, 8/SIMD) to hide the ~400-cyc L2
// B-load latency between MFMA bursts. LDS = single bf16 hi act plane
// (55 KB). Weights = global hi/lo planes (L2-hot), plain loads. 2-term
// split precision: acc += ah*bh + ah*bl. NaN guard: epi zeroes LDS cols
// [208,216) of every row + 16-short tail (NaN*0=NaN in MFMA).
template <bool READOUT>
__global__ __launch_bounds__(1024, 2) void fused_kernel(
    const short* __restrict__ Agh, int glda,
    const short* __restrict__ W1h, const short* __restrict__ W1l,
    const short* __restrict__ W2h, const short* __restrict__ W2l,
    const short* __restrict__ W3h, const short* __restrict__ W3l,
    const short* __restrict__ W4h, const short* __restrict__ W4l,
    const float* __restrict__ b1, const float* __restrict__ b2,
    const float* __restrict__ b3, const float* __restrict__ b4,
    unsigned* __restrict__ xp, short* __restrict__ xq, int t,
    const float* __restrict__ w4ro, const int* __restrict__ mol,
    float* __restrict__ out) {
  __shared__ short ldsH[128 * SP + 16];
  const int tid = threadIdx.x;
  const int wave = tid >> 6, lane = tid & 63, ln = lane & 15, quad = lane >> 4;
  const int wm = wave >> 2;   // M quarter: rows wm*32 .. wm*32+31
  const int wn = wave & 3;    // N quarter
  const int bm = blockIdx.x * 128;
  const int ntile = (wn == 0) ? 4 : 3;
  const int n0col = (wn == 0) ? 0 : 16 + wn * 48;  // 0, 64, 112, 160

  if (tid < 16) ldsH[128 * SP + tid] = 0;  // zero tail for row-127 k-overread

  f32x4 acc[2][4];

  auto layer = [&](auto ga_tag, const short* __restrict__ Wh,
                   const short* __restrict__ Wl, int Kpad, int KP) {
    constexpr bool GA = decltype(ga_tag)::value;
#pragma unroll
    for (int i = 0; i < 2; i++)
#pragma unroll
      for (int j = 0; j < 4; j++) acc[i][j] = (f32x4){0.f, 0.f, 0.f, 0.f};
    for (int k0 = 0; k0 < KP; k0 += 32) {
      short8b ah[2], bh[4], bl[4];
#pragma unroll
      for (int i = 0; i < 2; i++) {
        int r = wm * 32 + i * 16 + ln;
        if constexpr (GA)
          ah[i] = *(const short8b*)(Agh + (size_t)(bm + r) * glda + k0 + quad * 8);
        else
          ah[i] = *(const short8b*)(ldsH + r * SP + k0 + quad * 8);
      }
#pragma unroll
      for (int j = 0; j < 4; j++)
        if (j < ntile) {
          const size_t o = (size_t)(n0col + j * 16 + ln) * Kpad + k0 + quad * 8;
          bh[j] = *(const short8b*)(Wh + o);
          bl[j] = *(const short8b*)(Wl + o);
        }
#pragma unroll
      for (int j = 0; j < 4; j++)
        if (j < ntile)
#pragma unroll
          for (int i = 0; i < 2; i++) {
            acc[i][j] = __builtin_amdgcn_mfma_f32_16x16x32_bf16(ah[i], bh[j], acc[i][j], 0, 0, 0);
            acc[i][j] = __builtin_amdgcn_mfma_f32_16x16x32_bf16(ah[i], bl[j], acc[i][j], 0, 0, 0);
          }
    }
  };

  // epilogue: relu(acc+bias) -> hi plane; zero cols [208,216) of every row
  auto epi = [&](const float* __restrict__ bias) {
    __syncthreads();
#pragma unroll
    for (int i = 0; i < 2; i++)
#pragma unroll
      for (int j = 0; j < 4; j++)
        if (j < ntile)
#pragma unroll
          for (int r = 0; r < 4; r++) {
            int row = wm * 32 + i * 16 + quad * 4 + r;
            int col = n0col + j * 16 + ln;
            float v = acc[i][j][r] + (col < HH ? bias[col] : 0.f);
            v = fmaxf(v, 0.f);
            ldsH[row * SP + col] = (short)f2bf(v);
          }
    // NaN guard: cols 208..215 (8 threads/row x 1 short, 1024 thr = 128 rows)
    ldsH[(tid >> 3) * SP + 208 + (tid & 7)] = 0;
    __syncthreads();
  };

  if (!READOUT) {
    layer(std::true_type{}, W1h, W1l, 96, 96);
    epi(b1);
    layer(std::false_type{}, W2h, W2l, 224, 224);
    epi(b2);
    layer(std::false_type{}, W3h, W3l, 224, 224);
    epi(b3);
    // ---- L4 (200->64): 4M x 4N wave split; rows wm*32.., cols wn*16..+15 ----
    f32x4 a4[2];
#pragma unroll
    for (int i = 0; i < 2; i++) a4[i] = (f32x4){0.f, 0.f, 0.f, 0.f};
    for (int k0 = 0; k0 < 224; k0 += 32) {
      short8b ah[2], bh, bl;
#pragma unroll
      for (int i = 0; i < 2; i++) {
        int r = wm * 32 + i * 16 + ln;
        ah[i] = *(const short8b*)(ldsH + r * SP + k0 + quad * 8);
      }
      const size_t o = (size_t)(wn * 16 + ln) * 224 + k0 + quad * 8;
      bh = *(const short8b*)(W4h + o);
      bl = *(const short8b*)(W4l + o);
#pragma unroll
      for (int i = 0; i < 2; i++) {
        a4[i] = __builtin_amdgcn_mfma_f32_16x16x32_bf16(ah[i], bh, a4[i], 0, 0, 0);
        a4[i] = __builtin_amdgcn_mfma_f32_16x16x32_bf16(ah[i], bl, a4[i], 0, 0, 0);
      }
    }
    // x-update: x[t+1] = x[t] + 0.1*(h3@W4 + b4); also maintain hi-plane xq
#pragma unroll
    for (int i = 0; i < 2; i++)
#pragma unroll
      for (int r = 0; r < 4; r++) {
        int grow = bm + wm * 32 + i * 16 + quad * 4 + r;
        int col = wn * 16 + ln;
        if (grow < NN) {
          float v = a4[i][r] + b4[col];
          size_t base = (size_t)grow * RD;
          float old = bfp2f(xp[base + (size_t)t * ED + col]);
          unsigned pk = packsplit(old + 0.1f * v);
          xp[base + (size_t)(t + 1) * ED + col] = pk;
          xq[base + (size_t)(t + 1) * ED + col] = (short)(pk & 0xffffu);
        }
      }
  } else {
    layer(std::true_type{}, W1h, W1l, 256, 256);
    epi(b1);
    layer(std::false_type{}, W2h, W2l, 224, 224);
    epi(b2);
    layer(std::false_type{}, W3h, W3l, 224, 224);
    epi(b3);
    // fused final layer (200->1) + molecule segment-sum: 8 threads per row
    int row = tid >> 3;
    int grow = bm + row;
    float s = 0.f;
    for (int c = (tid & 7); c < HH; c += 8)
      s += ubf2f((unsigned short)ldsH[row * SP + c]) * w4ro[c];
    s += __shfl_xor(s, 1, 64);
    s += __shfl_xor(s, 2, 64);
    s += __shfl_xor(s, 4, 64);
    if ((tid & 7) == 0 && grow < NN) atomicAdd(&out[mol[grow]], s + b4[0]);
  }
}

// ---------------- host launcher ----------------
extern "C" void kernel_launch(void* const* d_in, const int* in_sizes, int n_in,
                              void* d_out, int out_size, void* d_ws, size_t ws_size,
                              hipStream_t stream) {
  const int* z_i = (const int*)d_in[0];
  const int* e_src = (const int*)d_in[1];
  const int* e_snk = ((const int*)d_in[1]) + EE;
  const float* dist = (const float*)d_in[2];
  const int* mol = (const int*)d_in[3];
  const float* emb = (const float*)d_in[4];
  const float* up_bn_g = (const float*)d_in[5];
  const float* up_bn_b = (const float*)d_in[6];
  const float* up_w1 = (const float*)d_in[7];
  const float* up_b1 = (const float*)d_in[8];
  const float* up_w2 = (const float*)d_in[9];
  const float* up_b2 = (const float*)d_in[10];
  const float* up_w3 = (const float*)d_in[11];
  const float* up_b3 = (const float*)d_in[12];
  const float* up_w4 = (const float*)d_in[13];
  const float* up_b4 = (const float*)d_in[14];
  const float* ro_bn_g = (const float*)d_in[15];
  const float* ro_bn_b = (const float*)d_in[16];
  const float* ro_w1 = (const float*)d_in[17];
  const float* ro_b1 = (const float*)d_in[18];
  const float* ro_w2 = (const float*)d_in[19];
  const float* ro_b2 = (const float*)d_in[20];
  const float* ro_w3 = (const float*)d_in[21];
  const float* ro_b3 = (const float*)d_in[22];
  const float* ro_w4 = (const float*)d_in[23];
  const float* ro_b4 = (const float*)d_in[24];
  float* out = (float*)d_out;

  char* p = (char*)d_ws;
  auto alloc = [&](size_t bytes) {
    void* r = (void*)p;
    p += (bytes + 255) & ~(size_t)255;
    return r;
  };
  unsigned* x_p = (unsigned*)alloc((size_t)NN * RD * 4);   // fp32-equiv pair
  short* x_q = (short*)alloc((size_t)NN * RD * 2);         // x hi plane (gather reads)
  unsigned* m_p = (unsigned*)alloc((size_t)NN * 96 * 4);
  short* mh = (short*)alloc((size_t)NP * 96 * 2);          // BN-applied m hi plane
  short* xh = (short*)alloc((size_t)NP * RD * 2);          // BN-applied x hi plane
  int* ssink = (int*)alloc((size_t)EE * 4);
  float* sdist = (float*)alloc((size_t)EE * 4);
  int* offs = (int*)alloc((size_t)(NN + 1) * 4);
  int* deg = (int*)alloc((size_t)NN * 4);
  int* cursor = (int*)alloc((size_t)NN * 4);
  int* Psum = (int*)alloc((size_t)SNB * 4);
  int* Poff = (int*)alloc((size_t)SNB * 4);
  float* P = (float*)alloc((size_t)NPB2 * 512 * 4);
  float* na = (float*)alloc(256 * 4);
  float* nb = (float*)alloc(256 * 4);
  // weight planes (transposed, padded)
  short* w1h = (short*)alloc((size_t)TT * 208 * 96 * 2);
  short* w1l = (short*)alloc((size_t)TT * 208 * 96 * 2);
  short* w2h = (short*)alloc((size_t)TT * 208 * 224 * 2);
  short* w2l = (short*)alloc((size_t)TT * 208 * 224 * 2);
  short* w3h = (short*)alloc((size_t)TT * 208 * 224 * 2);
  short* w3l = (short*)alloc((size_t)TT * 208 * 224 * 2);
  short* w4h = (short*)alloc((size_t)TT * 64 * 224 * 2);
  short* w4l = (short*)alloc((size_t)TT * 64 * 224 * 2);
  short* r1h = (short*)alloc((size_t)208 * 256 * 2);
  short* r1l = (short*)alloc((size_t)208 * 256 * 2);
  short* r2h = (short*)alloc((size_t)208 * 224 * 2);
  short* r2l = (short*)alloc((size_t)208 * 224 * 2);
  short* r3h = (short*)alloc((size_t)208 * 224 * 2);
  short* r3l = (short*)alloc((size_t)208 * 224 * 2);

  hipMemsetAsync(deg, 0, (size_t)NN * 4, stream);
  hipMemsetAsync(out, 0, (size_t)NMOL * 4, stream);

  WDs descs;
  descs.d[0] = {up_w1, w1h, w1l, MD, HH, 96, 208, TT};
  descs.d[1] = {up_w2, w2h, w2l, HH, HH, 224, 208, TT};
  descs.d[2] = {up_w3, w3h, w3l, HH, HH, 224, 208, TT};
  descs.d[3] = {up_w4, w4h, w4l, HH, ED, 224, 64, TT};
  descs.d[4] = {ro_w1, r1h, r1l, RD, HH, 256, 208, 1};
  descs.d[5] = {ro_w2, r2h, r2l, HH, HH, 224, 208, 1};
  descs.d[6] = {ro_w3, r3h, r3l, HH, HH, 224, 208, 1};
  wprep_kernel<<<dim3(546, 7), 256, 0, stream>>>(descs);

  emb_kernel<<<(NN * ED + 255) / 256, 256, 0, stream>>>(z_i, emb, x_p, x_q);
  hist_kernel<<<(EE + 255) / 256, 256, 0, stream>>>(e_src, deg);
  scanA_kernel<<<SNB, 256, 0, stream>>>(deg, Psum);
  scanB_kernel<<<1, 256, 0, stream>>>(Psum, Poff);
  scanC_kernel<<<SNB, 256, 0, stream>>>(deg, Poff, offs, cursor);
  scatter_kernel<<<(EE + 255) / 256, 256, 0, stream>>>(e_src, e_snk, dist, cursor, ssink, sdist);

  const int gM = NP / 128;  // 391

  for (int t = 0; t < TT; t++) {
    gather_kernel<<<(NN + 3) / 4, 256, 0, stream>>>(offs, ssink, sdist, x_q, t * ED, m_p);
    colstats2_kernel<96><<<NPB2, 256, 0, stream>>>(m_p, P);
    bnfinal2_kernel<<<256, 256, 0, stream>>>(P, NPB2, up_bn_g + t * MD, up_bn_b + t * MD, MD,
                                             na, nb);
    bnapply_kernel<96><<<(NP * 24 + 255) / 256, 256, 0, stream>>>(m_p, na, nb, mh);
    fused_kernel<false><<<gM, 1024, 0, stream>>>(
        mh, 96,
        w1h + (size_t)t * 208 * 96, w1l + (size_t)t * 208 * 96,
        w2h + (size_t)t * 208 * 224, w2l + (size_t)t * 208 * 224,
        w3h + (size_t)t * 208 * 224, w3l + (size_t)t * 208 * 224,
        w4h + (size_t)t * 64 * 224, w4l + (size_t)t * 64 * 224,
        up_b1 + t * HH, up_b2 + t * HH, up_b3 + t * HH, up_b4 + t * ED,
        x_p, x_q, t, nullptr, nullptr, nullptr);
  }

  colstats2_kernel<256><<<NPB2, 256, 0, stream>>>(x_p, P);
  bnfinal2_kernel<<<256, 256, 0, stream>>>(P, NPB2, ro_bn_g, ro_bn_b, RD, na, nb);
  bnapply_kernel<256><<<(NP * 64 + 255) / 256, 256, 0, stream>>>(x_p, na, nb, xh);
  fused_kernel<true><<<gM, 1024, 0, stream>>>(
      xh, 256,
      r1h, r1l, r2h, r2l, r3h, r3l, nullptr, nullptr,
      ro_b1, ro_b2, ro_b3, ro_b4,
      nullptr, nullptr, 0, ro_w4, mol, out);

  (void)in_sizes; (void)n_in; (void)out_size; (void)ws_size;
}

// Round 17
// 739.101 us; speedup vs baseline: 1.0986x; 1.0986x over previous
//
#include <hip/hip_runtime.h>
#include <hip/hip_bf16.h>
#include <type_traits>

#define NN 50000
#define NP 50048   // NN padded to 64*782
#define EE 800000
#define TT 3
#define ED 64
#define NS 23
#define MD 87
#define HH 200
#define NMOL 2048
#define RD 256

#define SP 216     // LDS act hi-plane stride (shorts)
#define BSP 36     // LDS B tile row stride (shorts): conflict-free b128
#define NPB2 512   // colstats partial blocks
#define SNB ((NN + 255) / 256)  // 196 scan blocks

typedef __attribute__((ext_vector_type(8))) short short8b;
typedef __attribute__((ext_vector_type(4))) short short4b;
typedef __attribute__((ext_vector_type(4))) float f32x4;

// ---- bf16 helpers ----
__device__ __forceinline__ unsigned short f2bf(float f) {
  unsigned u = __float_as_uint(f);
  return (unsigned short)((u + 0x7fffu + ((u >> 16) & 1u)) >> 16);
}
__device__ __forceinline__ float ubf2f(unsigned short h) {
  return __uint_as_float(((unsigned)h) << 16);
}
// interleaved pair in one u32: low16 = hi-bf16, high16 = lo-bf16 (fp32-equivalent)
__device__ __forceinline__ float bfp2f(unsigned p) {
  return __uint_as_float(p << 16) + __uint_as_float(p & 0xffff0000u);
}
__device__ __forceinline__ unsigned packsplit(float v) {
  unsigned short h = f2bf(v);
  unsigned short l = f2bf(v - ubf2f(h));
  return (unsigned)h | ((unsigned)l << 16);
}

// ---------------- weight prep: fp32 [T][K][N] -> bf16 hi/lo planes [T][Npad][Kpad] ----
struct WD { const float* src; short* dh; short* dl; int K, N, Kpad, Npad, T; };
struct WDs { WD d[7]; };

__global__ __launch_bounds__(256) void wprep_kernel(WDs W) {
  WD w = W.d[blockIdx.y];
  int per = w.Npad * w.Kpad;
  int total = w.T * per;
  for (int idx = blockIdx.x * 256 + threadIdx.x; idx < total; idx += gridDim.x * 256) {
    int t = idx / per;
    int r = idx - t * per;
    int n = r / w.Kpad;
    int k = r - n * w.Kpad;
    float v = 0.f;
    if (k < w.K && n < w.N) v = w.src[((size_t)t * w.K + k) * w.N + n];
    unsigned short h = f2bf(v);
    unsigned short l = f2bf(v - ubf2f(h));
    w.dh[idx] = (short)h;
    w.dl[idx] = (short)l;
  }
}

// ---------------- embedding -> x slice 0 (pair + hi plane) ----------------
__global__ __launch_bounds__(256) void emb_kernel(const int* __restrict__ z,
                                                  const float* __restrict__ emb,
                                                  unsigned* __restrict__ xp,
                                                  short* __restrict__ xq) {
  int idx = blockIdx.x * 256 + threadIdx.x;
  if (idx >= NN * ED) return;
  int i = idx >> 6, d = idx & 63;
  unsigned pk = packsplit(emb[z[i] * ED + d]);
  xp[(size_t)i * RD + d] = pk;
  xq[(size_t)i * RD + d] = (short)(pk & 0xffffu);
}

// ---------------- CSR build ----------------
__global__ __launch_bounds__(256) void hist_kernel(const int* __restrict__ src,
                                                   int* __restrict__ deg) {
  int e = blockIdx.x * 256 + threadIdx.x;
  if (e < EE) atomicAdd(&deg[src[e]], 1);
}

// 3-stage parallel exclusive scan of deg[0..NN)
__global__ __launch_bounds__(256) void scanA_kernel(const int* __restrict__ deg,
                                                    int* __restrict__ Psum) {
  int i = blockIdx.x * 256 + threadIdx.x;
  int v = (i < NN) ? deg[i] : 0;
#pragma unroll
  for (int off = 32; off > 0; off >>= 1) v += __shfl_down(v, off, 64);
  __shared__ int ws[4];
  if ((threadIdx.x & 63) == 0) ws[threadIdx.x >> 6] = v;
  __syncthreads();
  if (threadIdx.x == 0) Psum[blockIdx.x] = ws[0] + ws[1] + ws[2] + ws[3];
}

__global__ __launch_bounds__(256) void scanB_kernel(const int* __restrict__ Psum,
                                                    int* __restrict__ Poff) {
  __shared__ int sh[256];
  int t = threadIdx.x;
  int v = (t < SNB) ? Psum[t] : 0;
  sh[t] = v;
  __syncthreads();
  for (int off = 1; off < 256; off <<= 1) {
    int u = (t >= off) ? sh[t - off] : 0;
    __syncthreads();
    sh[t] += u;
    __syncthreads();
  }
  if (t < SNB) Poff[t] = sh[t] - v;  // exclusive
}

__global__ __launch_bounds__(256) void scanC_kernel(const int* __restrict__ deg,
                                                    const int* __restrict__ Poff,
                                                    int* __restrict__ offs,
                                                    int* __restrict__ cursor) {
  __shared__ int sh[256];
  int t = threadIdx.x;
  int i = blockIdx.x * 256 + t;
  int v = (i < NN) ? deg[i] : 0;
  sh[t] = v;
  __syncthreads();
  for (int off = 1; off < 256; off <<= 1) {
    int u = (t >= off) ? sh[t - off] : 0;
    __syncthreads();
    sh[t] += u;
    __syncthreads();
  }
  int excl = Poff[blockIdx.x] + sh[t] - v;
  if (i < NN) {
    offs[i] = excl;
    cursor[i] = excl;
    if (i == NN - 1) offs[NN] = excl + v;
  }
}

__global__ __launch_bounds__(256) void scatter_kernel(const int* __restrict__ src,
                                                      const int* __restrict__ snk,
                                                      const float* __restrict__ dist,
                                                      int* __restrict__ cursor,
                                                      int* __restrict__ ssink,
                                                      float* __restrict__ sdist) {
  int e = blockIdx.x * 256 + threadIdx.x;
  if (e >= EE) return;
  int p = atomicAdd(&cursor[src[e]], 1);
  ssink[p] = snk[e];
  sdist[p] = dist[e];
}

// ---------------- message gather: one wave per node, hi-plane reads ----------
__global__ __launch_bounds__(256) void gather_kernel(const int* __restrict__ offs,
                                                     const int* __restrict__ ssink,
                                                     const float* __restrict__ sdist,
                                                     const short* __restrict__ xq,
                                                     int toff, unsigned* __restrict__ m) {
  int node = blockIdx.x * 4 + (threadIdx.x >> 6);
  int lane = threadIdx.x & 63;
  if (node >= NN) return;
  float shift = (float)(0.8 + 0.1 * (double)lane);
  int e0 = offs[node], e1 = offs[node + 1];
  float ax0 = 0.f, ax1 = 0.f, ar0 = 0.f, ar1 = 0.f;
  int j = e0;
  for (; j + 4 <= e1; j += 4) {
    int s0 = ssink[j], s1 = ssink[j + 1], s2 = ssink[j + 2], s3 = ssink[j + 3];
    float d0 = sdist[j], d1 = sdist[j + 1], d2 = sdist[j + 2], d3 = sdist[j + 3];
    float x0 = ubf2f((unsigned short)xq[(size_t)s0 * RD + toff + lane]);
    float x1 = ubf2f((unsigned short)xq[(size_t)s1 * RD + toff + lane]);
    float x2 = ubf2f((unsigned short)xq[(size_t)s2 * RD + toff + lane]);
    float x3 = ubf2f((unsigned short)xq[(size_t)s3 * RD + toff + lane]);
    ax0 += x0 + x2;
    ax1 += x1 + x3;
    if (lane < NS) {
      float u0 = d0 - shift, u1 = d1 - shift, u2 = d2 - shift, u3 = d3 - shift;
      ar0 += __expf(-u0 * u0) + __expf(-u2 * u2);
      ar1 += __expf(-u1 * u1) + __expf(-u3 * u3);
    }
  }
  for (; j < e1; j++) {
    int s = ssink[j];
    float d = sdist[j];
    ax0 += ubf2f((unsigned short)xq[(size_t)s * RD + toff + lane]);
    if (lane < NS) {
      float u = d - shift;
      ar0 += __expf(-u * u);
    }
  }
  float accx = ax0 + ax1, accr = ar0 + ar1;
  if (lane < NS) m[node * 96 + lane] = packsplit(accr);
  m[node * 96 + NS + lane] = packsplit(accx);
}

// ---------------- batchnorm stats: stage 1 (vectorized, 512 blocks) ----------
template <int LD>
__global__ __launch_bounds__(256) void colstats2_kernel(const unsigned* __restrict__ X,
                                                        float* __restrict__ P) {
  constexpr int CG = LD / 4;
  constexpr int RPB = 256 / CG;
  const int t = threadIdx.x;
  const int cg = t % CG, rin = t / CG;
  float s0 = 0, s1 = 0, s2 = 0, s3 = 0, q0 = 0, q1 = 0, q2 = 0, q3 = 0;
  if (rin < RPB) {
    for (int r = blockIdx.x * RPB + rin; r < NN; r += gridDim.x * RPB) {
      uint4 v = *(const uint4*)(X + (size_t)r * LD + cg * 4);
      float f0 = bfp2f(v.x), f1 = bfp2f(v.y), f2 = bfp2f(v.z), f3 = bfp2f(v.w);
      s0 += f0; q0 += f0 * f0;
      s1 += f1; q1 += f1 * f1;
      s2 += f2; q2 += f2 * f2;
      s3 += f3; q3 += f3 * f3;
    }
  }
  __shared__ float sh[256][8];
  sh[t][0] = s0; sh[t][1] = s1; sh[t][2] = s2; sh[t][3] = s3;
  sh[t][4] = q0; sh[t][5] = q1; sh[t][6] = q2; sh[t][7] = q3;
  __syncthreads();
  if (rin == 0) {
#pragma unroll
    for (int rr = 1; rr < RPB; rr++) {
      const float* o = sh[rr * CG + cg];
      s0 += o[0]; s1 += o[1]; s2 += o[2]; s3 += o[3];
      q0 += o[4]; q1 += o[5]; q2 += o[6]; q3 += o[7];
    }
    float* Pb = P + blockIdx.x * 512;
    Pb[cg * 4 + 0] = s0; Pb[cg * 4 + 1] = s1; Pb[cg * 4 + 2] = s2; Pb[cg * 4 + 3] = s3;
    Pb[256 + cg * 4 + 0] = q0; Pb[256 + cg * 4 + 1] = q1;
    Pb[256 + cg * 4 + 2] = q2; Pb[256 + cg * 4 + 3] = q3;
  }
}

// ---------------- batchnorm stats: stage 2 (one block per column) ------------
__global__ __launch_bounds__(256) void bnfinal2_kernel(const float* __restrict__ P, int nblk,
                                                       const float* __restrict__ g,
                                                       const float* __restrict__ b, int ncols,
                                                       float* __restrict__ na,
                                                       float* __restrict__ nb) {
  int c = blockIdx.x;
  int t = threadIdx.x;
  float s = 0.f, q = 0.f;
  for (int i = t; i < nblk; i += 256) {
    s += P[i * 512 + c];
    q += P[i * 512 + 256 + c];
  }
#pragma unroll
  for (int off = 32; off > 0; off >>= 1) {
    s += __shfl_down(s, off, 64);
    q += __shfl_down(q, off, 64);
  }
  __shared__ float ws[4], wq[4];
  if ((t & 63) == 0) { ws[t >> 6] = s; wq[t >> 6] = q; }
  __syncthreads();
  if (t == 0) {
    s = ws[0] + ws[1] + ws[2] + ws[3];
    q = wq[0] + wq[1] + wq[2] + wq[3];
    if (c < ncols) {
      float mean = s / (float)NN;
      float var = q / (float)NN - mean * mean;
      float a = g[c] * rsqrtf(var + 1e-5f);
      na[c] = a;
      nb[c] = b[c] - mean * a;
    } else {
      na[c] = 0.f;  // pad cols -> BN-applied value 0
      nb[c] = 0.f;
    }
  }
}

// ---------------- BN apply: pair -> pre-normalized bf16 hi plane only --------
template <int LD>
__global__ __launch_bounds__(256) void bnapply_kernel(const unsigned* __restrict__ Xp,
                                                      const float* __restrict__ na,
                                                      const float* __restrict__ nb,
                                                      short* __restrict__ Xh) {
  int idx = blockIdx.x * 256 + threadIdx.x;  // over NP * LD/4
  if (idx >= NP * (LD / 4)) return;
  int row = idx / (LD / 4);
  int cg = (idx - row * (LD / 4)) * 4;
  short4b h;
  if (row < NN) {
    uint4 v = *(const uint4*)(Xp + (size_t)row * LD + cg);
    unsigned arr[4] = {v.x, v.y, v.z, v.w};
#pragma unroll
    for (int e = 0; e < 4; e++) {
      float f = bfp2f(arr[e]) * na[cg + e] + nb[cg + e];
      h[e] = (short)f2bf(f);
    }
  } else {
    h = (short4b){0, 0, 0, 0};
  }
  *(short4b*)(Xh + (size_t)row * LD + cg) = h;
}

// ---------------- fused MLP kernel ----------------
// R17: R15 shape (64-row tile, 512 thr, 8 waves N-split {2,2,2,2,2,1,1,1}
// tiles of 16 over 208 cols) + B STAGED THROUGH LDS each k-iter (per-thread
// uint4 load -> ds_write, single buffer, 2 barriers/iter = m93/m97 pattern).
// Rationale: R11-R16 all show per-wave global B loads serialize at full L2
// latency (MfmaUtil ~10%, all pipes idle) and no occupancy knob fixed it;
// staging converts 8 independent per-wave waits/iter into one collective
// wait that phase-offset co-resident blocks overlap. B rows padded to 36
// shorts -> conflict-free b128 frags. LDS 57.6 KB -> 2 blocks/CU.
// 2-term split precision: acc += ah*bh + ah*bl. NaN guard: epi zeroes act
// cols [208,216) + tail (NaN*0=NaN in MFMA); staged B is fully initialized.
template <bool READOUT>
__global__ __launch_bounds__(512, 4) void fused_kernel(
    const short* __restrict__ Agh, int glda,
    const short* __restrict__ W1h, const short* __restrict__ W1l,
    const short* __restrict__ W2h, const short* __restrict__ W2l,
    const short* __restrict__ W3h, const short* __restrict__ W3l,
    const short* __restrict__ W4h, const short* __restrict__ W4l,
    const float* __restrict__ b1, const float* __restrict__ b2,
    const float* __restrict__ b3, const float* __restrict__ b4,
    unsigned* __restrict__ xp, short* __restrict__ xq, int t,
    const float* __restrict__ w4ro, const int* __restrict__ mol,
    float* __restrict__ out) {
  __shared__ short ldsH[64 * SP + 16];   // act hi plane (27.7 KB)
  __shared__ short Bs[416 * BSP];        // B tile: hi rows 0..207, lo rows 208..415 (29.9 KB)
  const int tid = threadIdx.x;
  const int wave = tid >> 6, lane = tid & 63, ln = lane & 15, quad = lane >> 4;
  const int bm = blockIdx.x * 64;
  const int ntile = (wave < 5) ? 2 : 1;
  const int n0col = ((wave < 5) ? 2 * wave : wave + 5) * 16;  // 13 tiles of 16

  if (tid < 16) ldsH[64 * SP + tid] = 0;  // zero tail for row-63 k-overread

  f32x4 acc[4][2];

  auto layer = [&](auto ga_tag, const short* __restrict__ Wh,
                   const short* __restrict__ Wl, int Kpad, int KP) {
    constexpr bool GA = decltype(ga_tag)::value;
#pragma unroll
    for (int i = 0; i < 4; i++)
#pragma unroll
      for (int j = 0; j < 2; j++) acc[i][j] = (f32x4){0.f, 0.f, 0.f, 0.f};
    for (int k0 = 0; k0 < KP; k0 += 32) {
      // ---- stage B tile [208 hi + 208 lo rows] x 32 shorts into LDS ----
      __syncthreads();  // previous iter's Bs frag reads complete
      {
        auto ldB = [&](int c) -> uint4 {
          int row = c >> 2, seg = (c & 3) * 8;
          const short* src =
              (row < 208 ? Wh + (size_t)row * Kpad : Wl + (size_t)(row - 208) * Kpad) +
              k0 + seg;
          return *(const uint4*)src;
        };
        uint4 v0 = ldB(tid);
        uint4 v1 = ldB(tid + 512);
        uint4 v2 = ldB(tid + 1024);
        uint4 v3;
        bool h3 = (tid + 1536) < 1664;
        if (h3) v3 = ldB(tid + 1536);
        *(uint4*)(Bs + (tid >> 2) * BSP + (tid & 3) * 8) = v0;
        *(uint4*)(Bs + ((tid + 512) >> 2) * BSP + (tid & 3) * 8) = v1;
        *(uint4*)(Bs + ((tid + 1024) >> 2) * BSP + (tid & 3) * 8) = v2;
        if (h3) *(uint4*)(Bs + ((tid + 1536) >> 2) * BSP + (tid & 3) * 8) = v3;
      }
      __syncthreads();  // B tile visible
      // ---- A fragments ----
      short8b ah[4], bh[2], bl[2];
#pragma unroll
      for (int i = 0; i < 4; i++) {
        int r = i * 16 + ln;
        if constexpr (GA)
          ah[i] = *(const short8b*)(Agh + (size_t)(bm + r) * glda + k0 + quad * 8);
        else
          ah[i] = *(const short8b*)(ldsH + r * SP + k0 + quad * 8);
      }
      // ---- B fragments (LDS) + MFMA ----
#pragma unroll
      for (int j = 0; j < 2; j++)
        if (j < ntile) {
          int n = n0col + j * 16 + ln;
          bh[j] = *(const short8b*)(Bs + (size_t)n * BSP + quad * 8);
          bl[j] = *(const short8b*)(Bs + (size_t)(208 + n) * BSP + quad * 8);
        }
#pragma unroll
      for (int j = 0; j < 2; j++)
        if (j < ntile)
#pragma unroll
          for (int i = 0; i < 4; i++) {
            acc[i][j] = __builtin_amdgcn_mfma_f32_16x16x32_bf16(ah[i], bh[j], acc[i][j], 0, 0, 0);
            acc[i][j] = __builtin_amdgcn_mfma_f32_16x16x32_bf16(ah[i], bl[j], acc[i][j], 0, 0, 0);
          }
    }
  };

  // epilogue: relu(acc+bias) -> hi plane; zero cols [208,216) of every row
  auto epi = [&](const float* __restrict__ bias) {
    __syncthreads();
#pragma unroll
    for (int i = 0; i < 4; i++)
#pragma unroll
      for (int j = 0; j < 2; j++)
        if (j < ntile)
#pragma unroll
          for (int r = 0; r < 4; r++) {
            int row = i * 16 + quad * 4 + r;
            int col = n0col + j * 16 + ln;
            float v = acc[i][j][r] + (col < HH ? bias[col] : 0.f);
            v = fmaxf(v, 0.f);
            ldsH[row * SP + col] = (short)f2bf(v);
          }
    // NaN guard: cols 208..215 (8 threads/row x 1 short, 512 thr = 64 rows)
    ldsH[(tid >> 3) * SP + 208 + (tid & 7)] = 0;
    __syncthreads();
  };

  if (!READOUT) {
    layer(std::true_type{}, W1h, W1l, 96, 96);
    epi(b1);
    layer(std::false_type{}, W2h, W2l, 224, 224);
    epi(b2);
    layer(std::false_type{}, W3h, W3l, 224, 224);
    epi(b3);
    // ---- L4 (200->64): 2M x 4N wave split, B from global (small) ----
    const int wm4 = wave & 1, wn4 = wave >> 1;  // rows wm4*32.., cols wn4*16..
    f32x4 a4[2];
#pragma unroll
    for (int i = 0; i < 2; i++) a4[i] = (f32x4){0.f, 0.f, 0.f, 0.f};
    for (int k0 = 0; k0 < 224; k0 += 32) {
      short8b ah[2], bh, bl;
#pragma unroll
      for (int i = 0; i < 2; i++) {
        int r = wm4 * 32 + i * 16 + ln;
        ah[i] = *(const short8b*)(ldsH + r * SP + k0 + quad * 8);
      }
      const size_t o = (size_t)(wn4 * 16 + ln) * 224 + k0 + quad * 8;
      bh = *(const short8b*)(W4h + o);
      bl = *(const short8b*)(W4l + o);
#pragma unroll
      for (int i = 0; i < 2; i++) {
        a4[i] = __builtin_amdgcn_mfma_f32_16x16x32_bf16(ah[i], bh, a4[i], 0, 0, 0);
        a4[i] = __builtin_amdgcn_mfma_f32_16x16x32_bf16(ah[i], bl, a4[i], 0, 0, 0);
      }
    }
    // x-update: x[t+1] = x[t] + 0.1*(h3@W4 + b4); also maintain hi-plane xq
#pragma unroll
    for (int i = 0; i < 2; i++)
#pragma unroll
      for (int r = 0; r < 4; r++) {
        int grow = bm + wm4 * 32 + i * 16 + quad * 4 + r;
        int col = wn4 * 16 + ln;
        if (grow < NN) {
          float v = a4[i][r] + b4[col];
          size_t base = (size_t)grow * RD;
          float old = bfp2f(xp[base + (size_t)t * ED + col]);
          unsigned pk = packsplit(old + 0.1f * v);
          xp[base + (size_t)(t + 1) * ED + col] = pk;
          xq[base + (size_t)(t + 1) * ED + col] = (short)(pk & 0xffffu);
        }
      }
  } else {
    layer(std::true_type{}, W1h, W1l, 256, 256);
    epi(b1);
    layer(std::false_type{}, W2h, W2l, 224, 224);
    epi(b2);
    layer(std::false_type{}, W3h, W3l, 224, 224);
    epi(b3);
    // fused final layer (200->1) + molecule segment-sum: 8 threads per row
    int row = tid >> 3;
    int grow = bm + row;
    float s = 0.f;
    for (int c = (tid & 7); c < HH; c += 8)
      s += ubf2f((unsigned short)ldsH[row * SP + c]) * w4ro[c];
    s += __shfl_xor(s, 1, 64);
    s += __shfl_xor(s, 2, 64);
    s += __shfl_xor(s, 4, 64);
    if ((tid & 7) == 0 && grow < NN) atomicAdd(&out[mol[grow]], s + b4[0]);
  }
}

// ---------------- host launcher ----------------
extern "C" void kernel_launch(void* const* d_in, const int* in_sizes, int n_in,
                              void* d_out, int out_size, void* d_ws, size_t ws_size,
                              hipStream_t stream) {
  const int* z_i = (const int*)d_in[0];
  const int* e_src = (const int*)d_in[1];
  const int* e_snk = ((const int*)d_in[1]) + EE;
  const float* dist = (const float*)d_in[2];
  const int* mol = (const int*)d_in[3];
  const float* emb = (const float*)d_in[4];
  const float* up_bn_g = (const float*)d_in[5];
  const float* up_bn_b = (const float*)d_in[6];
  const float* up_w1 = (const float*)d_in[7];
  const float* up_b1 = (const float*)d_in[8];
  const float* up_w2 = (const float*)d_in[9];
  const float* up_b2 = (const float*)d_in[10];
  const float* up_w3 = (const float*)d_in[11];
  const float* up_b3 = (const float*)d_in[12];
  const float* up_w4 = (const float*)d_in[13];
  const float* up_b4 = (const float*)d_in[14];
  const float* ro_bn_g = (const float*)d_in[15];
  const float* ro_bn_b = (const float*)d_in[16];
  const float* ro_w1 = (const float*)d_in[17];
  const float* ro_b1 = (const float*)d_in[18];
  const float* ro_w2 = (const float*)d_in[19];
  const float* ro_b2 = (const float*)d_in[20];
  const float* ro_w3 = (const float*)d_in[21];
  const float* ro_b3 = (const float*)d_in[22];
  const float* ro_w4 = (const float*)d_in[23];
  const float* ro_b4 = (const float*)d_in[24];
  float* out = (float*)d_out;

  char* p = (char*)d_ws;
  auto alloc = [&](size_t bytes) {
    void* r = (void*)p;
    p += (bytes + 255) & ~(size_t)255;
    return r;
  };
  unsigned* x_p = (unsigned*)alloc((size_t)NN * RD * 4);   // fp32-equiv pair
  short* x_q = (short*)alloc((size_t)NN * RD * 2);         // x hi plane (gather reads)
  unsigned* m_p = (unsigned*)alloc((size_t)NN * 96 * 4);
  short* mh = (short*)alloc((size_t)NP * 96 * 2);          // BN-applied m hi plane
  short* xh = (short*)alloc((size_t)NP * RD * 2);          // BN-applied x hi plane
  int* ssink = (int*)alloc((size_t)EE * 4);
  float* sdist = (float*)alloc((size_t)EE * 4);
  int* offs = (int*)alloc((size_t)(NN + 1) * 4);
  int* deg = (int*)alloc((size_t)NN * 4);
  int* cursor = (int*)alloc((size_t)NN * 4);
  int* Psum = (int*)alloc((size_t)SNB * 4);
  int* Poff = (int*)alloc((size_t)SNB * 4);
  float* P = (float*)alloc((size_t)NPB2 * 512 * 4);
  float* na = (float*)alloc(256 * 4);
  float* nb = (float*)alloc(256 * 4);
  // weight planes (transposed, padded)
  short* w1h = (short*)alloc((size_t)TT * 208 * 96 * 2);
  short* w1l = (short*)alloc((size_t)TT * 208 * 96 * 2);
  short* w2h = (short*)alloc((size_t)TT * 208 * 224 * 2);
  short* w2l = (short*)alloc((size_t)TT * 208 * 224 * 2);
  short* w3h = (short*)alloc((size_t)TT * 208 * 224 * 2);
  short* w3l = (short*)alloc((size_t)TT * 208 * 224 * 2);
  short* w4h = (short*)alloc((size_t)TT * 64 * 224 * 2);
  short* w4l = (short*)alloc((size_t)TT * 64 * 224 * 2);
  short* r1h = (short*)alloc((size_t)208 * 256 * 2);
  short* r1l = (short*)alloc((size_t)208 * 256 * 2);
  short* r2h = (short*)alloc((size_t)208 * 224 * 2);
  short* r2l = (short*)alloc((size_t)208 * 224 * 2);
  short* r3h = (short*)alloc((size_t)208 * 224 * 2);
  short* r3l = (short*)alloc((size_t)208 * 224 * 2);

  hipMemsetAsync(deg, 0, (size_t)NN * 4, stream);
  hipMemsetAsync(out, 0, (size_t)NMOL * 4, stream);

  WDs descs;
  descs.d[0] = {up_w1, w1h, w1l, MD, HH, 96, 208, TT};
  descs.d[1] = {up_w2, w2h, w2l, HH, HH, 224, 208, TT};
  descs.d[2] = {up_w3, w3h, w3l, HH, HH, 224, 208, TT};
  descs.d[3] = {up_w4, w4h, w4l, HH, ED, 224, 64, TT};
  descs.d[4] = {ro_w1, r1h, r1l, RD, HH, 256, 208, 1};
  descs.d[5] = {ro_w2, r2h, r2l, HH, HH, 224, 208, 1};
  descs.d[6] = {ro_w3, r3h, r3l, HH, HH, 224, 208, 1};
  wprep_kernel<<<dim3(546, 7), 256, 0, stream>>>(descs);

  emb_kernel<<<(NN * ED + 255) / 256, 256, 0, stream>>>(z_i, emb, x_p, x_q);
  hist_kernel<<<(EE + 255) / 256, 256, 0, stream>>>(e_src, deg);
  scanA_kernel<<<SNB, 256, 0, stream>>>(deg, Psum);
  scanB_kernel<<<1, 256, 0, stream>>>(Psum, Poff);
  scanC_kernel<<<SNB, 256, 0, stream>>>(deg, Poff, offs, cursor);
  scatter_kernel<<<(EE + 255) / 256, 256, 0, stream>>>(e_src, e_snk, dist, cursor, ssink, sdist);

  const int gM = NP / 64;  // 782

  for (int t = 0; t < TT; t++) {
    gather_kernel<<<(NN + 3) / 4, 256, 0, stream>>>(offs, ssink, sdist, x_q, t * ED, m_p);
    colstats2_kernel<96><<<NPB2, 256, 0, stream>>>(m_p, P);
    bnfinal2_kernel<<<256, 256, 0, stream>>>(P, NPB2, up_bn_g + t * MD, up_bn_b + t * MD, MD,
                                             na, nb);
    bnapply_kernel<96><<<(NP * 24 + 255) / 256, 256, 0, stream>>>(m_p, na, nb, mh);
    fused_kernel<false><<<gM, 512, 0, stream>>>(
        mh, 96,
        w1h + (size_t)t * 208 * 96, w1l + (size_t)t * 208 * 96,
        w2h + (size_t)t * 208 * 224, w2l + (size_t)t * 208 * 224,
        w3h + (size_t)t * 208 * 224, w3l + (size_t)t * 208 * 224,
        w4h + (size_t)t * 64 * 224, w4l + (size_t)t * 64 * 224,
        up_b1 + t * HH, up_b2 + t * HH, up_b3 + t * HH, up_b4 + t * ED,
        x_p, x_q, t, nullptr, nullptr, nullptr);
  }

  colstats2_kernel<256><<<NPB2, 256, 0, stream>>>(x_p, P);
  bnfinal2_kernel<<<256, 256, 0, stream>>>(P, NPB2, ro_bn_g, ro_bn_b, RD, na, nb);
  bnapply_kernel<256><<<(NP * 64 + 255) / 256, 256, 0, stream>>>(x_p, na, nb, xh);
  fused_kernel<true><<<gM, 512, 0, stream>>>(
      xh, 256,
      r1h, r1l, r2h, r2l, r3h, r3l, nullptr, nullptr,
      ro_b1, ro_b2, ro_b3, ro_b4,
      nullptr, nullptr, 0, ro_w4, mol, out);

  (void)in_sizes; (void)n_in; (void)out_size; (void)ws_size;
}

// Round 18
// 684.967 us; speedup vs baseline: 1.1854x; 1.0790x over previous
//
#include <hip/hip_runtime.h>
#include <hip/hip_bf16.h>
#include <type_traits>

#define NN 50000
#define NP 50048   // NN padded to 64*782
#define EE 800000
#define TT 3
#define ED 64
#define NS 23
#define MD 87
#define HH 200
#define NMOL 2048
#define RD 256

#define SP 216     // LDS act hi-plane stride (shorts)
#define NPB2 512   // colstats partial blocks
#define SNB ((NN + 255) / 256)  // 196 scan blocks

typedef __attribute__((ext_vector_type(8))) short short8b;
typedef __attribute__((ext_vector_type(4))) short short4b;
typedef __attribute__((ext_vector_type(4))) float f32x4;

// ---- bf16 helpers ----
__device__ __forceinline__ unsigned short f2bf(float f) {
  unsigned u = __float_as_uint(f);
  return (unsigned short)((u + 0x7fffu + ((u >> 16) & 1u)) >> 16);
}
__device__ __forceinline__ float ubf2f(unsigned short h) {
  return __uint_as_float(((unsigned)h) << 16);
}
// interleaved pair in one u32: low16 = hi-bf16, high16 = lo-bf16 (fp32-equivalent)
__device__ __forceinline__ float bfp2f(unsigned p) {
  return __uint_as_float(p << 16) + __uint_as_float(p & 0xffff0000u);
}
__device__ __forceinline__ unsigned packsplit(float v) {
  unsigned short h = f2bf(v);
  unsigned short l = f2bf(v - ubf2f(h));
  return (unsigned)h | ((unsigned)l << 16);
}

// ---------------- weight prep: fp32 [T][K][N] -> bf16 hi/lo planes [T][Npad][Kpad] ----
// (only layers 2..4 + readout 2..3; layer-1 weights are BN-scaled per pass by wscale)
struct WD { const float* src; short* dh; short* dl; int K, N, Kpad, Npad, T; };
struct WDs { WD d[5]; };

__global__ __launch_bounds__(256) void wprep_kernel(WDs W) {
  WD w = W.d[blockIdx.y];
  int per = w.Npad * w.Kpad;
  int total = w.T * per;
  for (int idx = blockIdx.x * 256 + threadIdx.x; idx < total; idx += gridDim.x * 256) {
    int t = idx / per;
    int r = idx - t * per;
    int n = r / w.Kpad;
    int k = r - n * w.Kpad;
    float v = 0.f;
    if (k < w.K && n < w.N) v = w.src[((size_t)t * w.K + k) * w.N + n];
    unsigned short h = f2bf(v);
    unsigned short l = f2bf(v - ubf2f(h));
    w.dh[idx] = (short)h;
    w.dl[idx] = (short)l;
  }
}

// ---------------- BN-folded layer-1 weight scale ----------------
// h1 = relu((a.m) @ W + (c @ W + b)) = relu(m @ (diag(a)W) + b')
// wsh/wsl[n][k] = split(na[k]*W[k][n]); bc[n] = b[n] + sum_k nb[k]*W[k][n].
// One block per n (208: rows >= 200 zeroed).
__global__ __launch_bounds__(256) void wscale_kernel(const float* __restrict__ wsrc,
                                                     const float* __restrict__ na,
                                                     const float* __restrict__ nb,
                                                     const float* __restrict__ bsrc,
                                                     int K, int Kpad,
                                                     short* __restrict__ wsh,
                                                     short* __restrict__ wsl,
                                                     float* __restrict__ bc) {
  int n = blockIdx.x;   // 0..207
  int k = threadIdx.x;  // 0..255
  float contrib = 0.f;
  if (n < HH && k < K) {
    float w = wsrc[(size_t)k * HH + n];
    float v = na[k] * w;
    unsigned short h = f2bf(v);
    wsh[(size_t)n * Kpad + k] = (short)h;
    wsl[(size_t)n * Kpad + k] = (short)f2bf(v - ubf2f(h));
    contrib = nb[k] * w;
  } else if (k < Kpad) {
    wsh[(size_t)n * Kpad + k] = 0;
    wsl[(size_t)n * Kpad + k] = 0;
  }
  __shared__ float sh[256];
  sh[k] = contrib;
  __syncthreads();
  for (int off = 128; off > 0; off >>= 1) {
    if (k < off) sh[k] += sh[k + off];
    __syncthreads();
  }
  if (k == 0) bc[n] = (n < HH ? bsrc[n] : 0.f) + sh[0];
}

// ---------------- embedding -> x slice 0 (pair + hi plane) ----------------
__global__ __launch_bounds__(256) void emb_kernel(const int* __restrict__ z,
                                                  const float* __restrict__ emb,
                                                  unsigned* __restrict__ xp,
                                                  short* __restrict__ xq) {
  int idx = blockIdx.x * 256 + threadIdx.x;
  if (idx >= NN * ED) return;
  int i = idx >> 6, d = idx & 63;
  unsigned pk = packsplit(emb[z[i] * ED + d]);
  xp[(size_t)i * RD + d] = pk;
  xq[(size_t)i * RD + d] = (short)(pk & 0xffffu);
}

// ---------------- CSR build ----------------
__global__ __launch_bounds__(256) void hist_kernel(const int* __restrict__ src,
                                                   int* __restrict__ deg) {
  int e = blockIdx.x * 256 + threadIdx.x;
  if (e < EE) atomicAdd(&deg[src[e]], 1);
}

// 3-stage parallel exclusive scan of deg[0..NN)
__global__ __launch_bounds__(256) void scanA_kernel(const int* __restrict__ deg,
                                                    int* __restrict__ Psum) {
  int i = blockIdx.x * 256 + threadIdx.x;
  int v = (i < NN) ? deg[i] : 0;
#pragma unroll
  for (int off = 32; off > 0; off >>= 1) v += __shfl_down(v, off, 64);
  __shared__ int ws[4];
  if ((threadIdx.x & 63) == 0) ws[threadIdx.x >> 6] = v;
  __syncthreads();
  if (threadIdx.x == 0) Psum[blockIdx.x] = ws[0] + ws[1] + ws[2] + ws[3];
}

__global__ __launch_bounds__(256) void scanB_kernel(const int* __restrict__ Psum,
                                                    int* __restrict__ Poff) {
  __shared__ int sh[256];
  int t = threadIdx.x;
  int v = (t < SNB) ? Psum[t] : 0;
  sh[t] = v;
  __syncthreads();
  for (int off = 1; off < 256; off <<= 1) {
    int u = (t >= off) ? sh[t - off] : 0;
    __syncthreads();
    sh[t] += u;
    __syncthreads();
  }
  if (t < SNB) Poff[t] = sh[t] - v;  // exclusive
}

__global__ __launch_bounds__(256) void scanC_kernel(const int* __restrict__ deg,
                                                    const int* __restrict__ Poff,
                                                    int* __restrict__ offs,
                                                    int* __restrict__ cursor) {
  __shared__ int sh[256];
  int t = threadIdx.x;
  int i = blockIdx.x * 256 + t;
  int v = (i < NN) ? deg[i] : 0;
  sh[t] = v;
  __syncthreads();
  for (int off = 1; off < 256; off <<= 1) {
    int u = (t >= off) ? sh[t - off] : 0;
    __syncthreads();
    sh[t] += u;
    __syncthreads();
  }
  int excl = Poff[blockIdx.x] + sh[t] - v;
  if (i < NN) {
    offs[i] = excl;
    cursor[i] = excl;
    if (i == NN - 1) offs[NN] = excl + v;
  }
}

__global__ __launch_bounds__(256) void scatter_kernel(const int* __restrict__ src,
                                                      const int* __restrict__ snk,
                                                      const float* __restrict__ dist,
                                                      int* __restrict__ cursor,
                                                      int* __restrict__ ssink,
                                                      float* __restrict__ sdist) {
  int e = blockIdx.x * 256 + threadIdx.x;
  if (e >= EE) return;
  int p = atomicAdd(&cursor[src[e]], 1);
  ssink[p] = snk[e];
  sdist[p] = dist[e];
}

// ---------------- message gather: one wave per node, writes bf16-hi m plane ---
__global__ __launch_bounds__(256) void gather_kernel(const int* __restrict__ offs,
                                                     const int* __restrict__ ssink,
                                                     const float* __restrict__ sdist,
                                                     const short* __restrict__ xq,
                                                     int toff, short* __restrict__ mh) {
  int node = blockIdx.x * 4 + (threadIdx.x >> 6);
  int lane = threadIdx.x & 63;
  if (node >= NN) return;
  float shift = (float)(0.8 + 0.1 * (double)lane);
  int e0 = offs[node], e1 = offs[node + 1];
  float ax0 = 0.f, ax1 = 0.f, ar0 = 0.f, ar1 = 0.f;
  int j = e0;
  for (; j + 4 <= e1; j += 4) {
    int s0 = ssink[j], s1 = ssink[j + 1], s2 = ssink[j + 2], s3 = ssink[j + 3];
    float d0 = sdist[j], d1 = sdist[j + 1], d2 = sdist[j + 2], d3 = sdist[j + 3];
    float x0 = ubf2f((unsigned short)xq[(size_t)s0 * RD + toff + lane]);
    float x1 = ubf2f((unsigned short)xq[(size_t)s1 * RD + toff + lane]);
    float x2 = ubf2f((unsigned short)xq[(size_t)s2 * RD + toff + lane]);
    float x3 = ubf2f((unsigned short)xq[(size_t)s3 * RD + toff + lane]);
    ax0 += x0 + x2;
    ax1 += x1 + x3;
    if (lane < NS) {
      float u0 = d0 - shift, u1 = d1 - shift, u2 = d2 - shift, u3 = d3 - shift;
      ar0 += __expf(-u0 * u0) + __expf(-u2 * u2);
      ar1 += __expf(-u1 * u1) + __expf(-u3 * u3);
    }
  }
  for (; j < e1; j++) {
    int s = ssink[j];
    float d = sdist[j];
    ax0 += ubf2f((unsigned short)xq[(size_t)s * RD + toff + lane]);
    if (lane < NS) {
      float u = d - shift;
      ar0 += __expf(-u * u);
    }
  }
  float accx = ax0 + ax1, accr = ar0 + ar1;
  if (lane < NS) mh[(size_t)node * 96 + lane] = (short)f2bf(accr);
  mh[(size_t)node * 96 + NS + lane] = (short)f2bf(accx);
}

// ---------------- batchnorm stats on bf16 planes (vectorized, 512 blocks) ----
template <int LD>
__global__ __launch_bounds__(256) void colstats_s16_kernel(const short* __restrict__ X,
                                                           float* __restrict__ P) {
  constexpr int CG = LD / 8;     // 8-col groups
  constexpr int RPB = 256 / CG;
  const int t = threadIdx.x;
  const int cg = t % CG, rin = t / CG;
  float s[8] = {0, 0, 0, 0, 0, 0, 0, 0}, q[8] = {0, 0, 0, 0, 0, 0, 0, 0};
  if (rin < RPB) {
    for (int r = blockIdx.x * RPB + rin; r < NN; r += gridDim.x * RPB) {
      union { uint4 v; short e[8]; } u;
      u.v = *(const uint4*)(X + (size_t)r * LD + cg * 8);
#pragma unroll
      for (int e = 0; e < 8; e++) {
        float f = ubf2f((unsigned short)u.e[e]);
        s[e] += f;
        q[e] += f * f;
      }
    }
  }
  __shared__ float sh[256][16];
#pragma unroll
  for (int e = 0; e < 8; e++) { sh[t][e] = s[e]; sh[t][8 + e] = q[e]; }
  __syncthreads();
  if (rin == 0) {
    for (int rr = 1; rr < RPB; rr++) {
      const float* o = sh[rr * CG + cg];
#pragma unroll
      for (int e = 0; e < 8; e++) { s[e] += o[e]; q[e] += o[8 + e]; }
    }
    float* Pb = P + blockIdx.x * 512;
#pragma unroll
    for (int e = 0; e < 8; e++) {
      Pb[cg * 8 + e] = s[e];
      Pb[256 + cg * 8 + e] = q[e];
    }
  }
}

// ---------------- batchnorm stats: stage 2 (one block per column) ------------
__global__ __launch_bounds__(256) void bnfinal2_kernel(const float* __restrict__ P, int nblk,
                                                       const float* __restrict__ g,
                                                       const float* __restrict__ b, int ncols,
                                                       float* __restrict__ na,
                                                       float* __restrict__ nb) {
  int c = blockIdx.x;
  int t = threadIdx.x;
  float s = 0.f, q = 0.f;
  for (int i = t; i < nblk; i += 256) {
    s += P[i * 512 + c];
    q += P[i * 512 + 256 + c];
  }
#pragma unroll
  for (int off = 32; off > 0; off >>= 1) {
    s += __shfl_down(s, off, 64);
    q += __shfl_down(q, off, 64);
  }
  __shared__ float ws[4], wq[4];
  if ((t & 63) == 0) { ws[t >> 6] = s; wq[t >> 6] = q; }
  __syncthreads();
  if (t == 0) {
    s = ws[0] + ws[1] + ws[2] + ws[3];
    q = wq[0] + wq[1] + wq[2] + wq[3];
    if (c < ncols) {
      float mean = s / (float)NN;
      float var = q / (float)NN - mean * mean;
      float a = g[c] * rsqrtf(var + 1e-5f);
      na[c] = a;
      nb[c] = b[c] - mean * a;
    } else {
      na[c] = 0.f;
      nb[c] = 0.f;
    }
  }
}

// ---------------- fused MLP kernel (R15 structure) ----------------
// 64-node tile, 512 thr = 8 waves all N-split ({2,2,2,2,2,1,1,1} tiles of 16
// over 208 cols), acc[4][2]. Act in LDS as single bf16 hi plane (27.7 KB).
// Weights = global hi/lo planes (L2-hot), plain loads. Layer-1 weights are
// BN-pre-scaled (wscale) so A is the RAW bf16-hi m/x plane -- no bnapply pass.
// 2-term split precision: acc += ah*bh + ah*bl. NaN guard: epi zeroes act
// cols [208,216) + tail (NaN*0=NaN in MFMA).
template <bool READOUT>
__global__ __launch_bounds__(512, 4) void fused_kernel(
    const short* __restrict__ Agh, int glda,
    const short* __restrict__ W1h, const short* __restrict__ W1l,
    const short* __restrict__ W2h, const short* __restrict__ W2l,
    const short* __restrict__ W3h, const short* __restrict__ W3l,
    const short* __restrict__ W4h, const short* __restrict__ W4l,
    const float* __restrict__ b1, const float* __restrict__ b2,
    const float* __restrict__ b3, const float* __restrict__ b4,
    unsigned* __restrict__ xp, short* __restrict__ xq, int t,
    const float* __restrict__ w4ro, const int* __restrict__ mol,
    float* __restrict__ out) {
  __shared__ short ldsH[64 * SP + 16];
  const int tid = threadIdx.x;
  const int wave = tid >> 6, lane = tid & 63, ln = lane & 15, quad = lane >> 4;
  const int bm = blockIdx.x * 64;
  const int ntile = (wave < 5) ? 2 : 1;
  const int n0col = ((wave < 5) ? 2 * wave : wave + 5) * 16;  // 13 tiles of 16

  if (tid < 16) ldsH[64 * SP + tid] = 0;  // zero tail for row-63 k-overread

  f32x4 acc[4][2];

  auto layer = [&](auto ga_tag, const short* __restrict__ Wh,
                   const short* __restrict__ Wl, int Kpad, int KP) {
    constexpr bool GA = decltype(ga_tag)::value;
#pragma unroll
    for (int i = 0; i < 4; i++)
#pragma unroll
      for (int j = 0; j < 2; j++) acc[i][j] = (f32x4){0.f, 0.f, 0.f, 0.f};
    for (int k0 = 0; k0 < KP; k0 += 32) {
      short8b ah[4], bh[2], bl[2];
#pragma unroll
      for (int i = 0; i < 4; i++) {
        int r = i * 16 + ln;
        if constexpr (GA)
          ah[i] = *(const short8b*)(Agh + (size_t)(bm + r) * glda + k0 + quad * 8);
        else
          ah[i] = *(const short8b*)(ldsH + r * SP + k0 + quad * 8);
      }
#pragma unroll
      for (int j = 0; j < 2; j++)
        if (j < ntile) {
          const size_t o = (size_t)(n0col + j * 16 + ln) * Kpad + k0 + quad * 8;
          bh[j] = *(const short8b*)(Wh + o);
          bl[j] = *(const short8b*)(Wl + o);
        }
#pragma unroll
      for (int j = 0; j < 2; j++)
        if (j < ntile)
#pragma unroll
          for (int i = 0; i < 4; i++) {
            acc[i][j] = __builtin_amdgcn_mfma_f32_16x16x32_bf16(ah[i], bh[j], acc[i][j], 0, 0, 0);
            acc[i][j] = __builtin_amdgcn_mfma_f32_16x16x32_bf16(ah[i], bl[j], acc[i][j], 0, 0, 0);
          }
    }
  };

  // epilogue: relu(acc+bias) -> hi plane; zero cols [208,216) of every row
  auto epi = [&](const float* __restrict__ bias) {
    __syncthreads();
#pragma unroll
    for (int i = 0; i < 4; i++)
#pragma unroll
      for (int j = 0; j < 2; j++)
        if (j < ntile)
#pragma unroll
          for (int r = 0; r < 4; r++) {
            int row = i * 16 + quad * 4 + r;
            int col = n0col + j * 16 + ln;
            float v = acc[i][j][r] + (col < HH ? bias[col] : 0.f);
            v = fmaxf(v, 0.f);
            ldsH[row * SP + col] = (short)f2bf(v);
          }
    // NaN guard: cols 208..215 (8 threads/row x 1 short, 512 thr = 64 rows)
    ldsH[(tid >> 3) * SP + 208 + (tid & 7)] = 0;
    __syncthreads();
  };

  if (!READOUT) {
    layer(std::true_type{}, W1h, W1l, 96, 96);
    epi(b1);
    layer(std::false_type{}, W2h, W2l, 224, 224);
    epi(b2);
    layer(std::false_type{}, W3h, W3l, 224, 224);
    epi(b3);
    // ---- L4 (200->64): 2M x 4N wave split ----
    const int wm4 = wave & 1, wn4 = wave >> 1;  // rows wm4*32.., cols wn4*16..
    f32x4 a4[2];
#pragma unroll
    for (int i = 0; i < 2; i++) a4[i] = (f32x4){0.f, 0.f, 0.f, 0.f};
    for (int k0 = 0; k0 < 224; k0 += 32) {
      short8b ah[2], bh, bl;
#pragma unroll
      for (int i = 0; i < 2; i++) {
        int r = wm4 * 32 + i * 16 + ln;
        ah[i] = *(const short8b*)(ldsH + r * SP + k0 + quad * 8);
      }
      const size_t o = (size_t)(wn4 * 16 + ln) * 224 + k0 + quad * 8;
      bh = *(const short8b*)(W4h + o);
      bl = *(const short8b*)(W4l + o);
#pragma unroll
      for (int i = 0; i < 2; i++) {
        a4[i] = __builtin_amdgcn_mfma_f32_16x16x32_bf16(ah[i], bh, a4[i], 0, 0, 0);
        a4[i] = __builtin_amdgcn_mfma_f32_16x16x32_bf16(ah[i], bl, a4[i], 0, 0, 0);
      }
    }
    // x-update: x[t+1] = x[t] + 0.1*(h3@W4 + b4); also maintain hi-plane xq
#pragma unroll
    for (int i = 0; i < 2; i++)
#pragma unroll
      for (int r = 0; r < 4; r++) {
        int grow = bm + wm4 * 32 + i * 16 + quad * 4 + r;
        int col = wn4 * 16 + ln;
        if (grow < NN) {
          float v = a4[i][r] + b4[col];
          size_t base = (size_t)grow * RD;
          float old = bfp2f(xp[base + (size_t)t * ED + col]);
          unsigned pk = packsplit(old + 0.1f * v);
          xp[base + (size_t)(t + 1) * ED + col] = pk;
          xq[base + (size_t)(t + 1) * ED + col] = (short)(pk & 0xffffu);
        }
      }
  } else {
    layer(std::true_type{}, W1h, W1l, 256, 256);
    epi(b1);
    layer(std::false_type{}, W2h, W2l, 224, 224);
    epi(b2);
    layer(std::false_type{}, W3h, W3l, 224, 224);
    epi(b3);
    // fused final layer (200->1) + molecule segment-sum: 8 threads per row
    int row = tid >> 3;
    int grow = bm + row;
    float s = 0.f;
    for (int c = (tid & 7); c < HH; c += 8)
      s += ubf2f((unsigned short)ldsH[row * SP + c]) * w4ro[c];
    s += __shfl_xor(s, 1, 64);
    s += __shfl_xor(s, 2, 64);
    s += __shfl_xor(s, 4, 64);
    if ((tid & 7) == 0 && grow < NN) atomicAdd(&out[mol[grow]], s + b4[0]);
  }
}

// ---------------- host launcher ----------------
extern "C" void kernel_launch(void* const* d_in, const int* in_sizes, int n_in,
                              void* d_out, int out_size, void* d_ws, size_t ws_size,
                              hipStream_t stream) {
  const int* z_i = (const int*)d_in[0];
  const int* e_src = (const int*)d_in[1];
  const int* e_snk = ((const int*)d_in[1]) + EE;
  const float* dist = (const float*)d_in[2];
  const int* mol = (const int*)d_in[3];
  const float* emb = (const float*)d_in[4];
  const float* up_bn_g = (const float*)d_in[5];
  const float* up_bn_b = (const float*)d_in[6];
  const float* up_w1 = (const float*)d_in[7];
  const float* up_b1 = (const float*)d_in[8];
  const float* up_w2 = (const float*)d_in[9];
  const float* up_b2 = (const float*)d_in[10];
  const float* up_w3 = (const float*)d_in[11];
  const float* up_b3 = (const float*)d_in[12];
  const float* up_w4 = (const float*)d_in[13];
  const float* up_b4 = (const float*)d_in[14];
  const float* ro_bn_g = (const float*)d_in[15];
  const float* ro_bn_b = (const float*)d_in[16];
  const float* ro_w1 = (const float*)d_in[17];
  const float* ro_b1 = (const float*)d_in[18];
  const float* ro_w2 = (const float*)d_in[19];
  const float* ro_b2 = (const float*)d_in[20];
  const float* ro_w3 = (const float*)d_in[21];
  const float* ro_b3 = (const float*)d_in[22];
  const float* ro_w4 = (const float*)d_in[23];
  const float* ro_b4 = (const float*)d_in[24];
  float* out = (float*)d_out;

  char* p = (char*)d_ws;
  auto alloc = [&](size_t bytes) {
    void* r = (void*)p;
    p += (bytes + 255) & ~(size_t)255;
    return r;
  };
  unsigned* x_p = (unsigned*)alloc((size_t)NN * RD * 4);   // fp32-equiv pair
  short* x_q = (short*)alloc((size_t)NP * RD * 2);         // x hi plane (pad rows: poison, finite)
  short* mh = (short*)alloc((size_t)NP * 96 * 2);          // raw m hi plane
  int* ssink = (int*)alloc((size_t)EE * 4);
  float* sdist = (float*)alloc((size_t)EE * 4);
  int* offs = (int*)alloc((size_t)(NN + 1) * 4);
  int* deg = (int*)alloc((size_t)NN * 4);
  int* cursor = (int*)alloc((size_t)NN * 4);
  int* Psum = (int*)alloc((size_t)SNB * 4);
  int* Poff = (int*)alloc((size_t)SNB * 4);
  float* P = (float*)alloc((size_t)NPB2 * 512 * 4);
  float* na = (float*)alloc(256 * 4);
  float* nb = (float*)alloc(256 * 4);
  float* b1c = (float*)alloc(208 * 4);
  // BN-scaled layer-1 weight planes (per pass / readout, reused)
  short* w1sh = (short*)alloc((size_t)208 * 96 * 2);
  short* w1sl = (short*)alloc((size_t)208 * 96 * 2);
  short* r1sh = (short*)alloc((size_t)208 * 256 * 2);
  short* r1sl = (short*)alloc((size_t)208 * 256 * 2);
  // static weight planes (transposed, padded)
  short* w2h = (short*)alloc((size_t)TT * 208 * 224 * 2);
  short* w2l = (short*)alloc((size_t)TT * 208 * 224 * 2);
  short* w3h = (short*)alloc((size_t)TT * 208 * 224 * 2);
  short* w3l = (short*)alloc((size_t)TT * 208 * 224 * 2);
  short* w4h = (short*)alloc((size_t)TT * 64 * 224 * 2);
  short* w4l = (short*)alloc((size_t)TT * 64 * 224 * 2);
  short* r2h = (short*)alloc((size_t)208 * 224 * 2);
  short* r2l = (short*)alloc((size_t)208 * 224 * 2);
  short* r3h = (short*)alloc((size_t)208 * 224 * 2);
  short* r3l = (short*)alloc((size_t)208 * 224 * 2);

  hipMemsetAsync(deg, 0, (size_t)NN * 4, stream);
  hipMemsetAsync(out, 0, (size_t)NMOL * 4, stream);

  WDs descs;
  descs.d[0] = {up_w2, w2h, w2l, HH, HH, 224, 208, TT};
  descs.d[1] = {up_w3, w3h, w3l, HH, HH, 224, 208, TT};
  descs.d[2] = {up_w4, w4h, w4l, HH, ED, 224, 64, TT};
  descs.d[3] = {ro_w2, r2h, r2l, HH, HH, 224, 208, 1};
  descs.d[4] = {ro_w3, r3h, r3l, HH, HH, 224, 208, 1};
  wprep_kernel<<<dim3(546, 5), 256, 0, stream>>>(descs);

  emb_kernel<<<(NN * ED + 255) / 256, 256, 0, stream>>>(z_i, emb, x_p, x_q);
  hist_kernel<<<(EE + 255) / 256, 256, 0, stream>>>(e_src, deg);
  scanA_kernel<<<SNB, 256, 0, stream>>>(deg, Psum);
  scanB_kernel<<<1, 256, 0, stream>>>(Psum, Poff);
  scanC_kernel<<<SNB, 256, 0, stream>>>(deg, Poff, offs, cursor);
  scatter_kernel<<<(EE + 255) / 256, 256, 0, stream>>>(e_src, e_snk, dist, cursor, ssink, sdist);

  const int gM = NP / 64;  // 782

  for (int t = 0; t < TT; t++) {
    gather_kernel<<<(NN + 3) / 4, 256, 0, stream>>>(offs, ssink, sdist, x_q, t * ED, mh);
    colstats_s16_kernel<96><<<NPB2, 256, 0, stream>>>(mh, P);
    bnfinal2_kernel<<<256, 256, 0, stream>>>(P, NPB2, up_bn_g + t * MD, up_bn_b + t * MD, MD,
                                             na, nb);
    wscale_kernel<<<208, 256, 0, stream>>>(up_w1 + (size_t)t * MD * HH, na, nb,
                                           up_b1 + t * HH, MD, 96, w1sh, w1sl, b1c);
    fused_kernel<false><<<gM, 512, 0, stream>>>(
        mh, 96, w1sh, w1sl,
        w2h + (size_t)t * 208 * 224, w2l + (size_t)t * 208 * 224,
        w3h + (size_t)t * 208 * 224, w3l + (size_t)t * 208 * 224,
        w4h + (size_t)t * 64 * 224, w4l + (size_t)t * 64 * 224,
        b1c, up_b2 + t * HH, up_b3 + t * HH, up_b4 + t * ED,
        x_p, x_q, t, nullptr, nullptr, nullptr);
  }

  colstats_s16_kernel<256><<<NPB2, 256, 0, stream>>>(x_q, P);
  bnfinal2_kernel<<<256, 256, 0, stream>>>(P, NPB2, ro_bn_g, ro_bn_b, RD, na, nb);
  wscale_kernel<<<208, 256, 0, stream>>>(ro_w1, na, nb, ro_b1, RD, 256, r1sh, r1sl, b1c);
  fused_kernel<true><<<gM, 512, 0, stream>>>(
      x_q, 256, r1sh, r1sl,
      r2h, r2l, r3h, r3l, nullptr, nullptr,
      b1c, ro_b2, ro_b3, ro_b4,
      nullptr, nullptr, 0, ro_w4, mol, out);

  (void)in_sizes; (void)n_in; (void)out_size; (void)ws_size;
}

// Round 19
// 613.181 us; speedup vs baseline: 1.3242x; 1.1171x over previous
//
#include <hip/hip_runtime.h>
#include <hip/hip_bf16.h>
#include <type_traits>

#define NN 50000
#define NP 50048   // NN padded to 64*782
#define EE 800000
#define TT 3
#define ED 64
#define NS 23
#define MD 87
#define HH 200
#define NMOL 2048
#define RD 256

#define SP 216     // LDS act hi-plane stride (shorts)
#define NPB2 512   // colstats partial blocks
#define SNB ((NN + 255) / 256)  // 196 scan blocks

typedef __attribute__((ext_vector_type(8))) short short8b;
typedef __attribute__((ext_vector_type(4))) short short4b;
typedef __attribute__((ext_vector_type(4))) float f32x4;

// ---- bf16 helpers ----
__device__ __forceinline__ unsigned short f2bf(float f) {
  unsigned u = __float_as_uint(f);
  return (unsigned short)((u + 0x7fffu + ((u >> 16) & 1u)) >> 16);
}
__device__ __forceinline__ float ubf2f(unsigned short h) {
  return __uint_as_float(((unsigned)h) << 16);
}
// interleaved pair in one u32: low16 = hi-bf16, high16 = lo-bf16 (fp32-equivalent)
__device__ __forceinline__ float bfp2f(unsigned p) {
  return __uint_as_float(p << 16) + __uint_as_float(p & 0xffff0000u);
}
__device__ __forceinline__ unsigned packsplit(float v) {
  unsigned short h = f2bf(v);
  unsigned short l = f2bf(v - ubf2f(h));
  return (unsigned)h | ((unsigned)l << 16);
}

// ---------------- weight prep: fp32 [T][K][N] -> PACKED fragment-major planes -----
// Packed layout: per (tile of 16 n-rows, kblk of 32 cols): 1024 shorts =
// [512 hi][512 lo], each lane-linear: slot = lane*8+e where lane=quad*16+ln,
// n=tile*16+ln, k=kblk*32+quad*8+e. A wave's B-fragment load becomes ONE
// coalesced 1KB burst (R18 layout was 16-way 448-B-strided scatter).
struct WD { const float* src; short* dst; int K, N, Kpad, Npad, T; };
struct WDs { WD d[5]; };

__global__ __launch_bounds__(256) void wprep_kernel(WDs W) {
  WD w = W.d[blockIdx.y];
  int KB = w.Kpad >> 5, NT = w.Npad >> 4;
  int per = w.Npad * w.Kpad;  // == NT*KB*512
  int total = w.T * per;
  for (int idx = blockIdx.x * 256 + threadIdx.x; idx < total; idx += gridDim.x * 256) {
    int t = idx / per;
    int r = idx - t * per;
    int e = r & 7, lane = (r >> 3) & 63;
    int blk = r >> 9;
    int kb = blk % KB, tile = blk / KB;
    int ln = lane & 15, quad = lane >> 4;
    int n = tile * 16 + ln, k = kb * 32 + quad * 8 + e;
    float v = 0.f;
    if (k < w.K && n < w.N) v = w.src[((size_t)t * w.K + k) * w.N + n];
    unsigned short h = f2bf(v);
    unsigned short l = f2bf(v - ubf2f(h));
    size_t base = ((size_t)(t * NT + tile) * KB + kb) * 1024;
    w.dst[base + lane * 8 + e] = (short)h;
    w.dst[base + 512 + lane * 8 + e] = (short)l;
  }
}

// ---------------- BN-folded layer-1 weight scale (packed output) ----------------
// h1 = relu(m @ (diag(na)W) + b'), b'[n] = b[n] + sum_k nb[k]*W[k][n].
__global__ __launch_bounds__(256) void wscale_kernel(const float* __restrict__ wsrc,
                                                     const float* __restrict__ na,
                                                     const float* __restrict__ nb,
                                                     const float* __restrict__ bsrc,
                                                     int K, int Kpad,
                                                     short* __restrict__ wsp,
                                                     float* __restrict__ bc) {
  int n = blockIdx.x;   // 0..207
  int k = threadIdx.x;  // 0..255
  int KB = Kpad >> 5;
  int tile = n >> 4, ln = n & 15;
  float contrib = 0.f;
  if (k < Kpad) {
    float v = 0.f;
    if (n < HH && k < K) {
      float w = wsrc[(size_t)k * HH + n];
      v = na[k] * w;
      contrib = nb[k] * w;
    }
    unsigned short h = f2bf(v);
    unsigned short l = f2bf(v - ubf2f(h));
    int kb = k >> 5, quad = (k & 31) >> 3, e = k & 7;
    int lane = quad * 16 + ln;
    size_t base = ((size_t)tile * KB + kb) * 1024;
    wsp[base + lane * 8 + e] = (short)h;
    wsp[base + 512 + lane * 8 + e] = (short)l;
  }
  __shared__ float sh[256];
  sh[k] = contrib;
  __syncthreads();
  for (int off = 128; off > 0; off >>= 1) {
    if (k < off) sh[k] += sh[k + off];
    __syncthreads();
  }
  if (k == 0) bc[n] = (n < HH ? bsrc[n] : 0.f) + sh[0];
}

// ---------------- embedding -> x slice 0 (pair + hi plane) ----------------
__global__ __launch_bounds__(256) void emb_kernel(const int* __restrict__ z,
                                                  const float* __restrict__ emb,
                                                  unsigned* __restrict__ xp,
                                                  short* __restrict__ xq) {
  int idx = blockIdx.x * 256 + threadIdx.x;
  if (idx >= NN * ED) return;
  int i = idx >> 6, d = idx & 63;
  unsigned pk = packsplit(emb[z[i] * ED + d]);
  xp[(size_t)i * RD + d] = pk;
  xq[(size_t)i * RD + d] = (short)(pk & 0xffffu);
}

// ---------------- CSR build ----------------
__global__ __launch_bounds__(256) void hist_kernel(const int* __restrict__ src,
                                                   int* __restrict__ deg) {
  int e = blockIdx.x * 256 + threadIdx.x;
  if (e < EE) atomicAdd(&deg[src[e]], 1);
}

// 3-stage parallel exclusive scan of deg[0..NN)
__global__ __launch_bounds__(256) void scanA_kernel(const int* __restrict__ deg,
                                                    int* __restrict__ Psum) {
  int i = blockIdx.x * 256 + threadIdx.x;
  int v = (i < NN) ? deg[i] : 0;
#pragma unroll
  for (int off = 32; off > 0; off >>= 1) v += __shfl_down(v, off, 64);
  __shared__ int ws[4];
  if ((threadIdx.x & 63) == 0) ws[threadIdx.x >> 6] = v;
  __syncthreads();
  if (threadIdx.x == 0) Psum[blockIdx.x] = ws[0] + ws[1] + ws[2] + ws[3];
}

__global__ __launch_bounds__(256) void scanB_kernel(const int* __restrict__ Psum,
                                                    int* __restrict__ Poff) {
  __shared__ int sh[256];
  int t = threadIdx.x;
  int v = (t < SNB) ? Psum[t] : 0;
  sh[t] = v;
  __syncthreads();
  for (int off = 1; off < 256; off <<= 1) {
    int u = (t >= off) ? sh[t - off] : 0;
    __syncthreads();
    sh[t] += u;
    __syncthreads();
  }
  if (t < SNB) Poff[t] = sh[t] - v;  // exclusive
}

__global__ __launch_bounds__(256) void scanC_kernel(const int* __restrict__ deg,
                                                    const int* __restrict__ Poff,
                                                    int* __restrict__ offs,
                                                    int* __restrict__ cursor) {
  __shared__ int sh[256];
  int t = threadIdx.x;
  int i = blockIdx.x * 256 + t;
  int v = (i < NN) ? deg[i] : 0;
  sh[t] = v;
  __syncthreads();
  for (int off = 1; off < 256; off <<= 1) {
    int u = (t >= off) ? sh[t - off] : 0;
    __syncthreads();
    sh[t] += u;
    __syncthreads();
  }
  int excl = Poff[blockIdx.x] + sh[t] - v;
  if (i < NN) {
    offs[i] = excl;
    cursor[i] = excl;
    if (i == NN - 1) offs[NN] = excl + v;
  }
}

__global__ __launch_bounds__(256) void scatter_kernel(const int* __restrict__ src,
                                                      const int* __restrict__ snk,
                                                      const float* __restrict__ dist,
                                                      int* __restrict__ cursor,
                                                      int* __restrict__ ssink,
                                                      float* __restrict__ sdist) {
  int e = blockIdx.x * 256 + threadIdx.x;
  if (e >= EE) return;
  int p = atomicAdd(&cursor[src[e]], 1);
  ssink[p] = snk[e];
  sdist[p] = dist[e];
}

// ---------------- message gather: one wave per node, writes bf16-hi m plane ---
__global__ __launch_bounds__(256) void gather_kernel(const int* __restrict__ offs,
                                                     const int* __restrict__ ssink,
                                                     const float* __restrict__ sdist,
                                                     const short* __restrict__ xq,
                                                     int toff, short* __restrict__ mh) {
  int node = blockIdx.x * 4 + (threadIdx.x >> 6);
  int lane = threadIdx.x & 63;
  if (node >= NN) return;
  float shift = (float)(0.8 + 0.1 * (double)lane);
  int e0 = offs[node], e1 = offs[node + 1];
  float ax0 = 0.f, ax1 = 0.f, ar0 = 0.f, ar1 = 0.f;
  int j = e0;
  for (; j + 4 <= e1; j += 4) {
    int s0 = ssink[j], s1 = ssink[j + 1], s2 = ssink[j + 2], s3 = ssink[j + 3];
    float d0 = sdist[j], d1 = sdist[j + 1], d2 = sdist[j + 2], d3 = sdist[j + 3];
    float x0 = ubf2f((unsigned short)xq[(size_t)s0 * RD + toff + lane]);
    float x1 = ubf2f((unsigned short)xq[(size_t)s1 * RD + toff + lane]);
    float x2 = ubf2f((unsigned short)xq[(size_t)s2 * RD + toff + lane]);
    float x3 = ubf2f((unsigned short)xq[(size_t)s3 * RD + toff + lane]);
    ax0 += x0 + x2;
    ax1 += x1 + x3;
    if (lane < NS) {
      float u0 = d0 - shift, u1 = d1 - shift, u2 = d2 - shift, u3 = d3 - shift;
      ar0 += __expf(-u0 * u0) + __expf(-u2 * u2);
      ar1 += __expf(-u1 * u1) + __expf(-u3 * u3);
    }
  }
  for (; j < e1; j++) {
    int s = ssink[j];
    float d = sdist[j];
    ax0 += ubf2f((unsigned short)xq[(size_t)s * RD + toff + lane]);
    if (lane < NS) {
      float u = d - shift;
      ar0 += __expf(-u * u);
    }
  }
  float accx = ax0 + ax1, accr = ar0 + ar1;
  if (lane < NS) mh[(size_t)node * 96 + lane] = (short)f2bf(accr);
  mh[(size_t)node * 96 + NS + lane] = (short)f2bf(accx);
}

// ---------------- batchnorm stats on bf16 planes (vectorized, 512 blocks) ----
template <int LD>
__global__ __launch_bounds__(256) void colstats_s16_kernel(const short* __restrict__ X,
                                                           float* __restrict__ P) {
  constexpr int CG = LD / 8;     // 8-col groups
  constexpr int RPB = 256 / CG;
  const int t = threadIdx.x;
  const int cg = t % CG, rin = t / CG;
  float s[8] = {0, 0, 0, 0, 0, 0, 0, 0}, q[8] = {0, 0, 0, 0, 0, 0, 0, 0};
  if (rin < RPB) {
    for (int r = blockIdx.x * RPB + rin; r < NN; r += gridDim.x * RPB) {
      union { uint4 v; short e[8]; } u;
      u.v = *(const uint4*)(X + (size_t)r * LD + cg * 8);
#pragma unroll
      for (int e = 0; e < 8; e++) {
        float f = ubf2f((unsigned short)u.e[e]);
        s[e] += f;
        q[e] += f * f;
      }
    }
  }
  __shared__ float sh[256][16];
#pragma unroll
  for (int e = 0; e < 8; e++) { sh[t][e] = s[e]; sh[t][8 + e] = q[e]; }
  __syncthreads();
  if (rin == 0) {
    for (int rr = 1; rr < RPB; rr++) {
      const float* o = sh[rr * CG + cg];
#pragma unroll
      for (int e = 0; e < 8; e++) { s[e] += o[e]; q[e] += o[8 + e]; }
    }
    float* Pb = P + blockIdx.x * 512;
#pragma unroll
    for (int e = 0; e < 8; e++) {
      Pb[cg * 8 + e] = s[e];
      Pb[256 + cg * 8 + e] = q[e];
    }
  }
}

// ---------------- batchnorm stats: stage 2 (one block per column) ------------
__global__ __launch_bounds__(256) void bnfinal2_kernel(const float* __restrict__ P, int nblk,
                                                       const float* __restrict__ g,
                                                       const float* __restrict__ b, int ncols,
                                                       float* __restrict__ na,
                                                       float* __restrict__ nb) {
  int c = blockIdx.x;
  int t = threadIdx.x;
  float s = 0.f, q = 0.f;
  for (int i = t; i < nblk; i += 256) {
    s += P[i * 512 + c];
    q += P[i * 512 + 256 + c];
  }
#pragma unroll
  for (int off = 32; off > 0; off >>= 1) {
    s += __shfl_down(s, off, 64);
    q += __shfl_down(q, off, 64);
  }
  __shared__ float ws[4], wq[4];
  if ((t & 63) == 0) { ws[t >> 6] = s; wq[t >> 6] = q; }
  __syncthreads();
  if (t == 0) {
    s = ws[0] + ws[1] + ws[2] + ws[3];
    q = wq[0] + wq[1] + wq[2] + wq[3];
    if (c < ncols) {
      float mean = s / (float)NN;
      float var = q / (float)NN - mean * mean;
      float a = g[c] * rsqrtf(var + 1e-5f);
      na[c] = a;
      nb[c] = b[c] - mean * a;
    } else {
      na[c] = 0.f;
      nb[c] = 0.f;
    }
  }
}

// ---------------- fused MLP kernel (R15 shape, packed-B, mixed terms) --------
// 64-node tile, 512 thr = 8 waves all N-split ({2,2,2,2,2,1,1,1} tiles of 16
// over 208 cols), acc[4][2]. Act in LDS as single bf16 hi plane (27.7 KB).
// Weights PACKED fragment-major: a B-frag load is one lane-linear coalesced
// 1KB burst (hi at base+lane*8, lo at +512). L2/L3 use 1-TERM (ah*bh only):
// halves loads+MFMA in the 14 hottest k-iters; L1 (BN-scaled W) and L4
// (feeds accumulating x) keep 2-term. NaN guard: epi zeroes act cols
// [208,216) + tail (NaN*0=NaN in MFMA); packed pad weights are exact zeros.
template <bool READOUT>
__global__ __launch_bounds__(512, 4) void fused_kernel(
    const short* __restrict__ Agh, int glda,
    const short* __restrict__ W1p, int KB1,
    const short* __restrict__ W2p, const short* __restrict__ W3p,
    const short* __restrict__ W4p,
    const float* __restrict__ b1, const float* __restrict__ b2,
    const float* __restrict__ b3, const float* __restrict__ b4,
    unsigned* __restrict__ xp, short* __restrict__ xq, int t,
    const float* __restrict__ w4ro, const int* __restrict__ mol,
    float* __restrict__ out) {
  __shared__ short ldsH[64 * SP + 16];
  const int tid = threadIdx.x;
  const int wave = tid >> 6, lane = tid & 63, ln = lane & 15, quad = lane >> 4;
  const int bm = blockIdx.x * 64;
  const int ntile = (wave < 5) ? 2 : 1;
  const int tile0 = (wave < 5) ? 2 * wave : wave + 5;  // 13 tiles of 16
  const int n0col = tile0 * 16;

  if (tid < 16) ldsH[64 * SP + tid] = 0;  // zero tail for row-63 k-overread

  f32x4 acc[4][2];

  auto layer = [&](auto ga_tag, auto terms_tag, const short* __restrict__ Wp,
                   int KB, int KP) {
    constexpr bool GA = decltype(ga_tag)::value;
    constexpr int TERMS = decltype(terms_tag)::value;
#pragma unroll
    for (int i = 0; i < 4; i++)
#pragma unroll
      for (int j = 0; j < 2; j++) acc[i][j] = (f32x4){0.f, 0.f, 0.f, 0.f};
    for (int k0 = 0; k0 < KP; k0 += 32) {
      const int kb = k0 >> 5;
      short8b ah[4], bh[2], bl[2];
#pragma unroll
      for (int i = 0; i < 4; i++) {
        int r = i * 16 + ln;
        if constexpr (GA)
          ah[i] = *(const short8b*)(Agh + (size_t)(bm + r) * glda + k0 + quad * 8);
        else
          ah[i] = *(const short8b*)(ldsH + r * SP + k0 + quad * 8);
      }
#pragma unroll
      for (int j = 0; j < 2; j++)
        if (j < ntile) {
          const short* bp = Wp + ((size_t)((tile0 + j) * KB + kb)) * 1024 + lane * 8;
          bh[j] = *(const short8b*)bp;
          if constexpr (TERMS == 2) bl[j] = *(const short8b*)(bp + 512);
        }
#pragma unroll
      for (int j = 0; j < 2; j++)
        if (j < ntile)
#pragma unroll
          for (int i = 0; i < 4; i++) {
            acc[i][j] = __builtin_amdgcn_mfma_f32_16x16x32_bf16(ah[i], bh[j], acc[i][j], 0, 0, 0);
            if constexpr (TERMS == 2)
              acc[i][j] =
                  __builtin_amdgcn_mfma_f32_16x16x32_bf16(ah[i], bl[j], acc[i][j], 0, 0, 0);
          }
    }
  };

  // epilogue: relu(acc+bias) -> hi plane; zero cols [208,216) of every row
  auto epi = [&](const float* __restrict__ bias) {
    __syncthreads();
#pragma unroll
    for (int i = 0; i < 4; i++)
#pragma unroll
      for (int j = 0; j < 2; j++)
        if (j < ntile)
#pragma unroll
          for (int r = 0; r < 4; r++) {
            int row = i * 16 + quad * 4 + r;
            int col = n0col + j * 16 + ln;
            float v = acc[i][j][r] + (col < HH ? bias[col] : 0.f);
            v = fmaxf(v, 0.f);
            ldsH[row * SP + col] = (short)f2bf(v);
          }
    // NaN guard: cols 208..215 (8 threads/row x 1 short, 512 thr = 64 rows)
    ldsH[(tid >> 3) * SP + 208 + (tid & 7)] = 0;
    __syncthreads();
  };

  using one_t = std::integral_constant<int, 1>;
  using two_t = std::integral_constant<int, 2>;

  if (!READOUT) {
    layer(std::true_type{}, two_t{}, W1p, KB1, 96);
    epi(b1);
    layer(std::false_type{}, one_t{}, W2p, 7, 224);
    epi(b2);
    layer(std::false_type{}, one_t{}, W3p, 7, 224);
    epi(b3);
    // ---- L4 (200->64): 2M x 4N wave split, packed B, 2-term ----
    const int wm4 = wave & 1, wn4 = wave >> 1;  // rows wm4*32.., col tile wn4
    f32x4 a4[2];
#pragma unroll
    for (int i = 0; i < 2; i++) a4[i] = (f32x4){0.f, 0.f, 0.f, 0.f};
    for (int k0 = 0; k0 < 224; k0 += 32) {
      const int kb = k0 >> 5;
      short8b ah[2], bh, bl;
#pragma unroll
      for (int i = 0; i < 2; i++) {
        int r = wm4 * 32 + i * 16 + ln;
        ah[i] = *(const short8b*)(ldsH + r * SP + k0 + quad * 8);
      }
      const short* bp = W4p + ((size_t)(wn4 * 7 + kb)) * 1024 + lane * 8;
      bh = *(const short8b*)bp;
      bl = *(const short8b*)(bp + 512);
#pragma unroll
      for (int i = 0; i < 2; i++) {
        a4[i] = __builtin_amdgcn_mfma_f32_16x16x32_bf16(ah[i], bh, a4[i], 0, 0, 0);
        a4[i] = __builtin_amdgcn_mfma_f32_16x16x32_bf16(ah[i], bl, a4[i], 0, 0, 0);
      }
    }
    // x-update: x[t+1] = x[t] + 0.1*(h3@W4 + b4); also maintain hi-plane xq
#pragma unroll
    for (int i = 0; i < 2; i++)
#pragma unroll
      for (int r = 0; r < 4; r++) {
        int grow = bm + wm4 * 32 + i * 16 + quad * 4 + r;
        int col = wn4 * 16 + ln;
        if (grow < NN) {
          float v = a4[i][r] + b4[col];
          size_t base = (size_t)grow * RD;
          float old = bfp2f(xp[base + (size_t)t * ED + col]);
          unsigned pk = packsplit(old + 0.1f * v);
          xp[base + (size_t)(t + 1) * ED + col] = pk;
          xq[base + (size_t)(t + 1) * ED + col] = (short)(pk & 0xffffu);
        }
      }
  } else {
    layer(std::true_type{}, two_t{}, W1p, KB1, 256);
    epi(b1);
    layer(std::false_type{}, one_t{}, W2p, 7, 224);
    epi(b2);
    layer(std::false_type{}, one_t{}, W3p, 7, 224);
    epi(b3);
    // fused final layer (200->1) + molecule segment-sum: 8 threads per row
    int row = tid >> 3;
    int grow = bm + row;
    float s = 0.f;
    for (int c = (tid & 7); c < HH; c += 8)
      s += ubf2f((unsigned short)ldsH[row * SP + c]) * w4ro[c];
    s += __shfl_xor(s, 1, 64);
    s += __shfl_xor(s, 2, 64);
    s += __shfl_xor(s, 4, 64);
    if ((tid & 7) == 0 && grow < NN) atomicAdd(&out[mol[grow]], s + b4[0]);
  }
}

// ---------------- host launcher ----------------
extern "C" void kernel_launch(void* const* d_in, const int* in_sizes, int n_in,
                              void* d_out, int out_size, void* d_ws, size_t ws_size,
                              hipStream_t stream) {
  const int* z_i = (const int*)d_in[0];
  const int* e_src = (const int*)d_in[1];
  const int* e_snk = ((const int*)d_in[1]) + EE;
  const float* dist = (const float*)d_in[2];
  const int* mol = (const int*)d_in[3];
  const float* emb = (const float*)d_in[4];
  const float* up_bn_g = (const float*)d_in[5];
  const float* up_bn_b = (const float*)d_in[6];
  const float* up_w1 = (const float*)d_in[7];
  const float* up_b1 = (const float*)d_in[8];
  const float* up_w2 = (const float*)d_in[9];
  const float* up_b2 = (const float*)d_in[10];
  const float* up_w3 = (const float*)d_in[11];
  const float* up_b3 = (const float*)d_in[12];
  const float* up_w4 = (const float*)d_in[13];
  const float* up_b4 = (const float*)d_in[14];
  const float* ro_bn_g = (const float*)d_in[15];
  const float* ro_bn_b = (const float*)d_in[16];
  const float* ro_w1 = (const float*)d_in[17];
  const float* ro_b1 = (const float*)d_in[18];
  const float* ro_w2 = (const float*)d_in[19];
  const float* ro_b2 = (const float*)d_in[20];
  const float* ro_w3 = (const float*)d_in[21];
  const float* ro_b3 = (const float*)d_in[22];
  const float* ro_w4 = (const float*)d_in[23];
  const float* ro_b4 = (const float*)d_in[24];
  float* out = (float*)d_out;

  char* p = (char*)d_ws;
  auto alloc = [&](size_t bytes) {
    void* r = (void*)p;
    p += (bytes + 255) & ~(size_t)255;
    return r;
  };
  unsigned* x_p = (unsigned*)alloc((size_t)NN * RD * 4);   // fp32-equiv pair
  short* x_q = (short*)alloc((size_t)NP * RD * 2);         // x hi plane
  short* mh = (short*)alloc((size_t)NP * 96 * 2);          // raw m hi plane
  int* ssink = (int*)alloc((size_t)EE * 4);
  float* sdist = (float*)alloc((size_t)EE * 4);
  int* offs = (int*)alloc((size_t)(NN + 1) * 4);
  int* deg = (int*)alloc((size_t)NN * 4);
  int* cursor = (int*)alloc((size_t)NN * 4);
  int* Psum = (int*)alloc((size_t)SNB * 4);
  int* Poff = (int*)alloc((size_t)SNB * 4);
  float* P = (float*)alloc((size_t)NPB2 * 512 * 4);
  float* na = (float*)alloc(256 * 4);
  float* nb = (float*)alloc(256 * 4);
  float* b1c = (float*)alloc(208 * 4);
  // packed layer-1 (BN-scaled per pass / readout)
  short* w1sp = (short*)alloc((size_t)13 * 3 * 1024 * 2);
  short* r1sp = (short*)alloc((size_t)13 * 8 * 1024 * 2);
  // packed static weights
  short* w2p = (short*)alloc((size_t)TT * 13 * 7 * 1024 * 2);
  short* w3p = (short*)alloc((size_t)TT * 13 * 7 * 1024 * 2);
  short* w4p = (short*)alloc((size_t)TT * 4 * 7 * 1024 * 2);
  short* r2p = (short*)alloc((size_t)13 * 7 * 1024 * 2);
  short* r3p = (short*)alloc((size_t)13 * 7 * 1024 * 2);

  hipMemsetAsync(deg, 0, (size_t)NN * 4, stream);
  hipMemsetAsync(out, 0, (size_t)NMOL * 4, stream);

  WDs descs;
  descs.d[0] = {up_w2, w2p, HH, HH, 224, 208, TT};
  descs.d[1] = {up_w3, w3p, HH, HH, 224, 208, TT};
  descs.d[2] = {up_w4, w4p, HH, ED, 224, 64, TT};
  descs.d[3] = {ro_w2, r2p, HH, HH, 224, 208, 1};
  descs.d[4] = {ro_w3, r3p, HH, HH, 224, 208, 1};
  wprep_kernel<<<dim3(546, 5), 256, 0, stream>>>(descs);

  emb_kernel<<<(NN * ED + 255) / 256, 256, 0, stream>>>(z_i, emb, x_p, x_q);
  hist_kernel<<<(EE + 255) / 256, 256, 0, stream>>>(e_src, deg);
  scanA_kernel<<<SNB, 256, 0, stream>>>(deg, Psum);
  scanB_kernel<<<1, 256, 0, stream>>>(Psum, Poff);
  scanC_kernel<<<SNB, 256, 0, stream>>>(deg, Poff, offs, cursor);
  scatter_kernel<<<(EE + 255) / 256, 256, 0, stream>>>(e_src, e_snk, dist, cursor, ssink, sdist);

  const int gM = NP / 64;  // 782

  for (int t = 0; t < TT; t++) {
    gather_kernel<<<(NN + 3) / 4, 256, 0, stream>>>(offs, ssink, sdist, x_q, t * ED, mh);
    colstats_s16_kernel<96><<<NPB2, 256, 0, stream>>>(mh, P);
    bnfinal2_kernel<<<256, 256, 0, stream>>>(P, NPB2, up_bn_g + t * MD, up_bn_b + t * MD, MD,
                                             na, nb);
    wscale_kernel<<<208, 256, 0, stream>>>(up_w1 + (size_t)t * MD * HH, na, nb,
                                           up_b1 + t * HH, MD, 96, w1sp, b1c);
    fused_kernel<false><<<gM, 512, 0, stream>>>(
        mh, 96, w1sp, 3,
        w2p + (size_t)t * 13 * 7 * 1024, w3p + (size_t)t * 13 * 7 * 1024,
        w4p + (size_t)t * 4 * 7 * 1024,
        b1c, up_b2 + t * HH, up_b3 + t * HH, up_b4 + t * ED,
        x_p, x_q, t, nullptr, nullptr, nullptr);
  }

  colstats_s16_kernel<256><<<NPB2, 256, 0, stream>>>(x_q, P);
  bnfinal2_kernel<<<256, 256, 0, stream>>>(P, NPB2, ro_bn_g, ro_bn_b, RD, na, nb);
  wscale_kernel<<<208, 256, 0, stream>>>(ro_w1, na, nb, ro_b1, RD, 256, r1sp, b1c);
  fused_kernel<true><<<gM, 512, 0, stream>>>(
      x_q, 256, r1sp, 8,
      r2p, r3p, nullptr,
      b1c, ro_b2, ro_b3, ro_b4,
      nullptr, nullptr, 0, ro_w4, mol, out);

  (void)in_sizes; (void)n_in; (void)out_size; (void)ws_size;
}

// Round 20
// 593.442 us; speedup vs baseline: 1.3683x; 1.0333x over previous
//
#include <hip/hip_runtime.h>
#include <hip/hip_bf16.h>
#include <type_traits>

#define NN 50000
#define NP 50048   // NN padded to 64*782
#define EE 800000
#define TT 3
#define ED 64
#define NS 23
#define MD 87
#define HH 200
#define NMOL 2048
#define RD 256

#define SP 216     // LDS act hi-plane stride (shorts)
#define NPB2 512   // colstats partial blocks
#define SNB ((NN + 255) / 256)  // 196 scan blocks

typedef __attribute__((ext_vector_type(8))) short short8b;
typedef __attribute__((ext_vector_type(4))) short short4b;
typedef __attribute__((ext_vector_type(4))) float f32x4;

// ---- bf16 helpers ----
__device__ __forceinline__ unsigned short f2bf(float f) {
  unsigned u = __float_as_uint(f);
  return (unsigned short)((u + 0x7fffu + ((u >> 16) & 1u)) >> 16);
}
__device__ __forceinline__ float ubf2f(unsigned short h) {
  return __uint_as_float(((unsigned)h) << 16);
}
// interleaved pair in one u32: low16 = hi-bf16, high16 = lo-bf16 (fp32-equivalent)
__device__ __forceinline__ float bfp2f(unsigned p) {
  return __uint_as_float(p << 16) + __uint_as_float(p & 0xffff0000u);
}
__device__ __forceinline__ unsigned packsplit(float v) {
  unsigned short h = f2bf(v);
  unsigned short l = f2bf(v - ubf2f(h));
  return (unsigned)h | ((unsigned)l << 16);
}

// ---------------- weight prep: fp32 [T][K][N] -> PACKED fragment-major planes -----
// Packed layout: per (tile of 16 n-rows, kblk of 32 cols): 1024 shorts =
// [512 hi][512 lo], lane-linear (slot = lane*8+e, lane = quad*16+ln,
// n = tile*16+ln, k = kblk*32+quad*8+e). B-frag load = ONE coalesced 1KB burst.
struct WD { const float* src; short* dst; int K, N, Kpad, Npad, T; };
struct WDs { WD d[5]; };

__global__ __launch_bounds__(256) void wprep_kernel(WDs W) {
  WD w = W.d[blockIdx.y];
  int KB = w.Kpad >> 5, NT = w.Npad >> 4;
  int per = w.Npad * w.Kpad;  // == NT*KB*512
  int total = w.T * per;
  for (int idx = blockIdx.x * 256 + threadIdx.x; idx < total; idx += gridDim.x * 256) {
    int t = idx / per;
    int r = idx - t * per;
    int e = r & 7, lane = (r >> 3) & 63;
    int blk = r >> 9;
    int kb = blk % KB, tile = blk / KB;
    int ln = lane & 15, quad = lane >> 4;
    int n = tile * 16 + ln, k = kb * 32 + quad * 8 + e;
    float v = 0.f;
    if (k < w.K && n < w.N) v = w.src[((size_t)t * w.K + k) * w.N + n];
    unsigned short h = f2bf(v);
    unsigned short l = f2bf(v - ubf2f(h));
    size_t base = ((size_t)(t * NT + tile) * KB + kb) * 1024;
    w.dst[base + lane * 8 + e] = (short)h;
    w.dst[base + 512 + lane * 8 + e] = (short)l;
  }
}

// ---------------- BN-folded layer-1 weight scale (packed output) ----------------
__global__ __launch_bounds__(256) void wscale_kernel(const float* __restrict__ wsrc,
                                                     const float* __restrict__ na,
                                                     const float* __restrict__ nb,
                                                     const float* __restrict__ bsrc,
                                                     int K, int Kpad,
                                                     short* __restrict__ wsp,
                                                     float* __restrict__ bc) {
  int n = blockIdx.x;   // 0..207
  int k = threadIdx.x;  // 0..255
  int KB = Kpad >> 5;
  int tile = n >> 4, ln = n & 15;
  float contrib = 0.f;
  if (k < Kpad) {
    float v = 0.f;
    if (n < HH && k < K) {
      float w = wsrc[(size_t)k * HH + n];
      v = na[k] * w;
      contrib = nb[k] * w;
    }
    unsigned short h = f2bf(v);
    unsigned short l = f2bf(v - ubf2f(h));
    int kb = k >> 5, quad = (k & 31) >> 3, e = k & 7;
    int lane = quad * 16 + ln;
    size_t base = ((size_t)tile * KB + kb) * 1024;
    wsp[base + lane * 8 + e] = (short)h;
    wsp[base + 512 + lane * 8 + e] = (short)l;
  }
  __shared__ float sh[256];
  sh[k] = contrib;
  __syncthreads();
  for (int off = 128; off > 0; off >>= 1) {
    if (k < off) sh[k] += sh[k + off];
    __syncthreads();
  }
  if (k == 0) bc[n] = (n < HH ? bsrc[n] : 0.f) + sh[0];
}

// ---------------- embedding -> x slice 0 (pair + row plane + slice plane) ----
__global__ __launch_bounds__(256) void emb_kernel(const int* __restrict__ z,
                                                  const float* __restrict__ emb,
                                                  unsigned* __restrict__ xp,
                                                  short* __restrict__ xq,
                                                  short* __restrict__ xqs) {
  int idx = blockIdx.x * 256 + threadIdx.x;
  if (idx >= NN * ED) return;
  int i = idx >> 6, d = idx & 63;
  unsigned pk = packsplit(emb[z[i] * ED + d]);
  xp[(size_t)i * RD + d] = pk;
  short h = (short)(pk & 0xffffu);
  xq[(size_t)i * RD + d] = h;
  xqs[(size_t)i * ED + d] = h;  // slice 0
}

// ---------------- CSR build ----------------
__global__ __launch_bounds__(256) void hist_kernel(const int* __restrict__ src,
                                                   int* __restrict__ deg) {
  int e = blockIdx.x * 256 + threadIdx.x;
  if (e < EE) atomicAdd(&deg[src[e]], 1);
}

// 3-stage parallel exclusive scan of deg[0..NN)
__global__ __launch_bounds__(256) void scanA_kernel(const int* __restrict__ deg,
                                                    int* __restrict__ Psum) {
  int i = blockIdx.x * 256 + threadIdx.x;
  int v = (i < NN) ? deg[i] : 0;
#pragma unroll
  for (int off = 32; off > 0; off >>= 1) v += __shfl_down(v, off, 64);
  __shared__ int ws[4];
  if ((threadIdx.x & 63) == 0) ws[threadIdx.x >> 6] = v;
  __syncthreads();
  if (threadIdx.x == 0) Psum[blockIdx.x] = ws[0] + ws[1] + ws[2] + ws[3];
}

__global__ __launch_bounds__(256) void scanB_kernel(const int* __restrict__ Psum,
                                                    int* __restrict__ Poff) {
  __shared__ int sh[256];
  int t = threadIdx.x;
  int v = (t < SNB) ? Psum[t] : 0;
  sh[t] = v;
  __syncthreads();
  for (int off = 1; off < 256; off <<= 1) {
    int u = (t >= off) ? sh[t - off] : 0;
    __syncthreads();
    sh[t] += u;
    __syncthreads();
  }
  if (t < SNB) Poff[t] = sh[t] - v;  // exclusive
}

__global__ __launch_bounds__(256) void scanC_kernel(const int* __restrict__ deg,
                                                    const int* __restrict__ Poff,
                                                    int* __restrict__ offs,
                                                    int* __restrict__ cursor) {
  __shared__ int sh[256];
  int t = threadIdx.x;
  int i = blockIdx.x * 256 + t;
  int v = (i < NN) ? deg[i] : 0;
  sh[t] = v;
  __syncthreads();
  for (int off = 1; off < 256; off <<= 1) {
    int u = (t >= off) ? sh[t - off] : 0;
    __syncthreads();
    sh[t] += u;
    __syncthreads();
  }
  int excl = Poff[blockIdx.x] + sh[t] - v;
  if (i < NN) {
    offs[i] = excl;
    cursor[i] = excl;
    if (i == NN - 1) offs[NN] = excl + v;
  }
}

__global__ __launch_bounds__(256) void scatter_kernel(const int* __restrict__ src,
                                                      const int* __restrict__ snk,
                                                      const float* __restrict__ dist,
                                                      int* __restrict__ cursor,
                                                      int* __restrict__ ssink,
                                                      float* __restrict__ sdist) {
  int e = blockIdx.x * 256 + threadIdx.x;
  if (e >= EE) return;
  int p = atomicAdd(&cursor[src[e]], 1);
  ssink[p] = snk[e];
  sdist[p] = dist[e];
}

// ---------------- message gather: one wave per node ----------------
// Reads SLICE-MAJOR xqs (6.4 MB working set -> L2-resident; R19 row-major
// spanned 25.6 MB). RBF sums (m cols 0..22) are pass-invariant (dist fixed):
// computed only when RBF=true (t=0); later passes reuse them in mh.
template <bool RBF>
__global__ __launch_bounds__(256) void gather_kernel(const int* __restrict__ offs,
                                                     const int* __restrict__ ssink,
                                                     const float* __restrict__ sdist,
                                                     const short* __restrict__ xqs,
                                                     short* __restrict__ mh) {
  int node = blockIdx.x * 4 + (threadIdx.x >> 6);
  int lane = threadIdx.x & 63;
  if (node >= NN) return;
  float shift = (float)(0.8 + 0.1 * (double)lane);
  int e0 = offs[node], e1 = offs[node + 1];
  float ax0 = 0.f, ax1 = 0.f, ar0 = 0.f, ar1 = 0.f;
  int j = e0;
  for (; j + 4 <= e1; j += 4) {
    int s0 = ssink[j], s1 = ssink[j + 1], s2 = ssink[j + 2], s3 = ssink[j + 3];
    float x0 = ubf2f((unsigned short)xqs[(size_t)s0 * ED + lane]);
    float x1 = ubf2f((unsigned short)xqs[(size_t)s1 * ED + lane]);
    float x2 = ubf2f((unsigned short)xqs[(size_t)s2 * ED + lane]);
    float x3 = ubf2f((unsigned short)xqs[(size_t)s3 * ED + lane]);
    ax0 += x0 + x2;
    ax1 += x1 + x3;
    if (RBF && lane < NS) {
      float d0 = sdist[j], d1 = sdist[j + 1], d2 = sdist[j + 2], d3 = sdist[j + 3];
      float u0 = d0 - shift, u1 = d1 - shift, u2 = d2 - shift, u3 = d3 - shift;
      ar0 += __expf(-u0 * u0) + __expf(-u2 * u2);
      ar1 += __expf(-u1 * u1) + __expf(-u3 * u3);
    }
  }
  for (; j < e1; j++) {
    int s = ssink[j];
    ax0 += ubf2f((unsigned short)xqs[(size_t)s * ED + lane]);
    if (RBF && lane < NS) {
      float u = sdist[j] - shift;
      ar0 += __expf(-u * u);
    }
  }
  float accx = ax0 + ax1;
  if (RBF && lane < NS) mh[(size_t)node * 96 + lane] = (short)f2bf(ar0 + ar1);
  mh[(size_t)node * 96 + NS + lane] = (short)f2bf(accx);
}

// ---------------- batchnorm stats on bf16 planes (vectorized, 512 blocks) ----
template <int LD>
__global__ __launch_bounds__(256) void colstats_s16_kernel(const short* __restrict__ X,
                                                           float* __restrict__ P) {
  constexpr int CG = LD / 8;     // 8-col groups
  constexpr int RPB = 256 / CG;
  const int t = threadIdx.x;
  const int cg = t % CG, rin = t / CG;
  float s[8] = {0, 0, 0, 0, 0, 0, 0, 0}, q[8] = {0, 0, 0, 0, 0, 0, 0, 0};
  if (rin < RPB) {
    for (int r = blockIdx.x * RPB + rin; r < NN; r += gridDim.x * RPB) {
      union { uint4 v; short e[8]; } u;
      u.v = *(const uint4*)(X + (size_t)r * LD + cg * 8);
#pragma unroll
      for (int e = 0; e < 8; e++) {
        float f = ubf2f((unsigned short)u.e[e]);
        s[e] += f;
        q[e] += f * f;
      }
    }
  }
  __shared__ float sh[256][16];
#pragma unroll
  for (int e = 0; e < 8; e++) { sh[t][e] = s[e]; sh[t][8 + e] = q[e]; }
  __syncthreads();
  if (rin == 0) {
    for (int rr = 1; rr < RPB; rr++) {
      const float* o = sh[rr * CG + cg];
#pragma unroll
      for (int e = 0; e < 8; e++) { s[e] += o[e]; q[e] += o[8 + e]; }
    }
    float* Pb = P + blockIdx.x * 512;
#pragma unroll
    for (int e = 0; e < 8; e++) {
      Pb[cg * 8 + e] = s[e];
      Pb[256 + cg * 8 + e] = q[e];
    }
  }
}

// ---------------- batchnorm stats: stage 2 (one block per column) ------------
__global__ __launch_bounds__(256) void bnfinal2_kernel(const float* __restrict__ P, int nblk,
                                                       const float* __restrict__ g,
                                                       const float* __restrict__ b, int ncols,
                                                       float* __restrict__ na,
                                                       float* __restrict__ nb) {
  int c = blockIdx.x;
  int t = threadIdx.x;
  float s = 0.f, q = 0.f;
  for (int i = t; i < nblk; i += 256) {
    s += P[i * 512 + c];
    q += P[i * 512 + 256 + c];
  }
#pragma unroll
  for (int off = 32; off > 0; off >>= 1) {
    s += __shfl_down(s, off, 64);
    q += __shfl_down(q, off, 64);
  }
  __shared__ float ws[4], wq[4];
  if ((t & 63) == 0) { ws[t >> 6] = s; wq[t >> 6] = q; }
  __syncthreads();
  if (t == 0) {
    s = ws[0] + ws[1] + ws[2] + ws[3];
    q = wq[0] + wq[1] + wq[2] + wq[3];
    if (c < ncols) {
      float mean = s / (float)NN;
      float var = q / (float)NN - mean * mean;
      float a = g[c] * rsqrtf(var + 1e-5f);
      na[c] = a;
      nb[c] = b[c] - mean * a;
    } else {
      na[c] = 0.f;
      nb[c] = 0.f;
    }
  }
}

// ---------------- fused MLP kernel (R19: packed-B, mixed terms) --------------
template <bool READOUT>
__global__ __launch_bounds__(512, 4) void fused_kernel(
    const short* __restrict__ Agh, int glda,
    const short* __restrict__ W1p, int KB1,
    const short* __restrict__ W2p, const short* __restrict__ W3p,
    const short* __restrict__ W4p,
    const float* __restrict__ b1, const float* __restrict__ b2,
    const float* __restrict__ b3, const float* __restrict__ b4,
    unsigned* __restrict__ xp, short* __restrict__ xq, short* __restrict__ xqs,
    int t, const float* __restrict__ w4ro, const int* __restrict__ mol,
    float* __restrict__ out) {
  __shared__ short ldsH[64 * SP + 16];
  const int tid = threadIdx.x;
  const int wave = tid >> 6, lane = tid & 63, ln = lane & 15, quad = lane >> 4;
  const int bm = blockIdx.x * 64;
  const int ntile = (wave < 5) ? 2 : 1;
  const int tile0 = (wave < 5) ? 2 * wave : wave + 5;  // 13 tiles of 16
  const int n0col = tile0 * 16;

  if (tid < 16) ldsH[64 * SP + tid] = 0;  // zero tail for row-63 k-overread

  f32x4 acc[4][2];

  auto layer = [&](auto ga_tag, auto terms_tag, const short* __restrict__ Wp,
                   int KB, int KP) {
    constexpr bool GA = decltype(ga_tag)::value;
    constexpr int TERMS = decltype(terms_tag)::value;
#pragma unroll
    for (int i = 0; i < 4; i++)
#pragma unroll
      for (int j = 0; j < 2; j++) acc[i][j] = (f32x4){0.f, 0.f, 0.f, 0.f};
    for (int k0 = 0; k0 < KP; k0 += 32) {
      const int kb = k0 >> 5;
      short8b ah[4], bh[2], bl[2];
#pragma unroll
      for (int i = 0; i < 4; i++) {
        int r = i * 16 + ln;
        if constexpr (GA)
          ah[i] = *(const short8b*)(Agh + (size_t)(bm + r) * glda + k0 + quad * 8);
        else
          ah[i] = *(const short8b*)(ldsH + r * SP + k0 + quad * 8);
      }
#pragma unroll
      for (int j = 0; j < 2; j++)
        if (j < ntile) {
          const short* bp = Wp + ((size_t)((tile0 + j) * KB + kb)) * 1024 + lane * 8;
          bh[j] = *(const short8b*)bp;
          if constexpr (TERMS == 2) bl[j] = *(const short8b*)(bp + 512);
        }
#pragma unroll
      for (int j = 0; j < 2; j++)
        if (j < ntile)
#pragma unroll
          for (int i = 0; i < 4; i++) {
            acc[i][j] = __builtin_amdgcn_mfma_f32_16x16x32_bf16(ah[i], bh[j], acc[i][j], 0, 0, 0);
            if constexpr (TERMS == 2)
              acc[i][j] =
                  __builtin_amdgcn_mfma_f32_16x16x32_bf16(ah[i], bl[j], acc[i][j], 0, 0, 0);
          }
    }
  };

  // epilogue: relu(acc+bias) -> hi plane; zero cols [208,216) of every row
  auto epi = [&](const float* __restrict__ bias) {
    __syncthreads();
#pragma unroll
    for (int i = 0; i < 4; i++)
#pragma unroll
      for (int j = 0; j < 2; j++)
        if (j < ntile)
#pragma unroll
          for (int r = 0; r < 4; r++) {
            int row = i * 16 + quad * 4 + r;
            int col = n0col + j * 16 + ln;
            float v = acc[i][j][r] + (col < HH ? bias[col] : 0.f);
            v = fmaxf(v, 0.f);
            ldsH[row * SP + col] = (short)f2bf(v);
          }
    // NaN guard: cols 208..215 (8 threads/row x 1 short, 512 thr = 64 rows)
    ldsH[(tid >> 3) * SP + 208 + (tid & 7)] = 0;
    __syncthreads();
  };

  using one_t = std::integral_constant<int, 1>;
  using two_t = std::integral_constant<int, 2>;

  if (!READOUT) {
    layer(std::true_type{}, two_t{}, W1p, KB1, 96);
    epi(b1);
    layer(std::false_type{}, one_t{}, W2p, 7, 224);
    epi(b2);
    layer(std::false_type{}, one_t{}, W3p, 7, 224);
    epi(b3);
    // ---- L4 (200->64): 2M x 4N wave split, packed B, 2-term ----
    const int wm4 = wave & 1, wn4 = wave >> 1;  // rows wm4*32.., col tile wn4
    f32x4 a4[2];
#pragma unroll
    for (int i = 0; i < 2; i++) a4[i] = (f32x4){0.f, 0.f, 0.f, 0.f};
    for (int k0 = 0; k0 < 224; k0 += 32) {
      const int kb = k0 >> 5;
      short8b ah[2], bh, bl;
#pragma unroll
      for (int i = 0; i < 2; i++) {
        int r = wm4 * 32 + i * 16 + ln;
        ah[i] = *(const short8b*)(ldsH + r * SP + k0 + quad * 8);
      }
      const short* bp = W4p + ((size_t)(wn4 * 7 + kb)) * 1024 + lane * 8;
      bh = *(const short8b*)bp;
      bl = *(const short8b*)(bp + 512);
#pragma unroll
      for (int i = 0; i < 2; i++) {
        a4[i] = __builtin_amdgcn_mfma_f32_16x16x32_bf16(ah[i], bh, a4[i], 0, 0, 0);
        a4[i] = __builtin_amdgcn_mfma_f32_16x16x32_bf16(ah[i], bl, a4[i], 0, 0, 0);
      }
    }
    // x-update: x[t+1] = x[t] + 0.1*(h3@W4 + b4); maintain row plane + slice plane
#pragma unroll
    for (int i = 0; i < 2; i++)
#pragma unroll
      for (int r = 0; r < 4; r++) {
        int grow = bm + wm4 * 32 + i * 16 + quad * 4 + r;
        int col = wn4 * 16 + ln;
        if (grow < NN) {
          float v = a4[i][r] + b4[col];
          size_t base = (size_t)grow * RD;
          float old = bfp2f(xp[base + (size_t)t * ED + col]);
          unsigned pk = packsplit(old + 0.1f * v);
          xp[base + (size_t)(t + 1) * ED + col] = pk;
          short h = (short)(pk & 0xffffu);
          xq[base + (size_t)(t + 1) * ED + col] = h;
          xqs[(size_t)(t + 1) * NN * ED + (size_t)grow * ED + col] = h;
        }
      }
  } else {
    layer(std::true_type{}, two_t{}, W1p, KB1, 256);
    epi(b1);
    layer(std::false_type{}, one_t{}, W2p, 7, 224);
    epi(b2);
    layer(std::false_type{}, one_t{}, W3p, 7, 224);
    epi(b3);
    // fused final layer (200->1) + molecule segment-sum: 8 threads per row
    int row = tid >> 3;
    int grow = bm + row;
    float s = 0.f;
    for (int c = (tid & 7); c < HH; c += 8)
      s += ubf2f((unsigned short)ldsH[row * SP + c]) * w4ro[c];
    s += __shfl_xor(s, 1, 64);
    s += __shfl_xor(s, 2, 64);
    s += __shfl_xor(s, 4, 64);
    if ((tid & 7) == 0 && grow < NN) atomicAdd(&out[mol[grow]], s + b4[0]);
  }
}

// ---------------- host launcher ----------------
extern "C" void kernel_launch(void* const* d_in, const int* in_sizes, int n_in,
                              void* d_out, int out_size, void* d_ws, size_t ws_size,
                              hipStream_t stream) {
  const int* z_i = (const int*)d_in[0];
  const int* e_src = (const int*)d_in[1];
  const int* e_snk = ((const int*)d_in[1]) + EE;
  const float* dist = (const float*)d_in[2];
  const int* mol = (const int*)d_in[3];
  const float* emb = (const float*)d_in[4];
  const float* up_bn_g = (const float*)d_in[5];
  const float* up_bn_b = (const float*)d_in[6];
  const float* up_w1 = (const float*)d_in[7];
  const float* up_b1 = (const float*)d_in[8];
  const float* up_w2 = (const float*)d_in[9];
  const float* up_b2 = (const float*)d_in[10];
  const float* up_w3 = (const float*)d_in[11];
  const float* up_b3 = (const float*)d_in[12];
  const float* up_w4 = (const float*)d_in[13];
  const float* up_b4 = (const float*)d_in[14];
  const float* ro_bn_g = (const float*)d_in[15];
  const float* ro_bn_b = (const float*)d_in[16];
  const float* ro_w1 = (const float*)d_in[17];
  const float* ro_b1 = (const float*)d_in[18];
  const float* ro_w2 = (const float*)d_in[19];
  const float* ro_b2 = (const float*)d_in[20];
  const float* ro_w3 = (const float*)d_in[21];
  const float* ro_b3 = (const float*)d_in[22];
  const float* ro_w4 = (const float*)d_in[23];
  const float* ro_b4 = (const float*)d_in[24];
  float* out = (float*)d_out;

  char* p = (char*)d_ws;
  auto alloc = [&](size_t bytes) {
    void* r = (void*)p;
    p += (bytes + 255) & ~(size_t)255;
    return r;
  };
  unsigned* x_p = (unsigned*)alloc((size_t)NN * RD * 4);     // fp32-equiv pair
  short* x_q = (short*)alloc((size_t)NP * RD * 2);           // x hi plane (row-major)
  short* x_qs = (short*)alloc((size_t)(TT + 1) * NN * ED * 2);  // x hi SLICE-major (gather)
  short* mh = (short*)alloc((size_t)NP * 96 * 2);            // raw m hi plane
  int* ssink = (int*)alloc((size_t)EE * 4);
  float* sdist = (float*)alloc((size_t)EE * 4);
  int* offs = (int*)alloc((size_t)(NN + 1) * 4);
  int* deg = (int*)alloc((size_t)NN * 4);
  int* cursor = (int*)alloc((size_t)NN * 4);
  int* Psum = (int*)alloc((size_t)SNB * 4);
  int* Poff = (int*)alloc((size_t)SNB * 4);
  float* P = (float*)alloc((size_t)NPB2 * 512 * 4);
  float* na = (float*)alloc(256 * 4);
  float* nb = (float*)alloc(256 * 4);
  float* b1c = (float*)alloc(208 * 4);
  // packed layer-1 (BN-scaled per pass / readout)
  short* w1sp = (short*)alloc((size_t)13 * 3 * 1024 * 2);
  short* r1sp = (short*)alloc((size_t)13 * 8 * 1024 * 2);
  // packed static weights
  short* w2p = (short*)alloc((size_t)TT * 13 * 7 * 1024 * 2);
  short* w3p = (short*)alloc((size_t)TT * 13 * 7 * 1024 * 2);
  short* w4p = (short*)alloc((size_t)TT * 4 * 7 * 1024 * 2);
  short* r2p = (short*)alloc((size_t)13 * 7 * 1024 * 2);
  short* r3p = (short*)alloc((size_t)13 * 7 * 1024 * 2);

  hipMemsetAsync(deg, 0, (size_t)NN * 4, stream);
  hipMemsetAsync(out, 0, (size_t)NMOL * 4, stream);

  WDs descs;
  descs.d[0] = {up_w2, w2p, HH, HH, 224, 208, TT};
  descs.d[1] = {up_w3, w3p, HH, HH, 224, 208, TT};
  descs.d[2] = {up_w4, w4p, HH, ED, 224, 64, TT};
  descs.d[3] = {ro_w2, r2p, HH, HH, 224, 208, 1};
  descs.d[4] = {ro_w3, r3p, HH, HH, 224, 208, 1};
  wprep_kernel<<<dim3(546, 5), 256, 0, stream>>>(descs);

  emb_kernel<<<(NN * ED + 255) / 256, 256, 0, stream>>>(z_i, emb, x_p, x_q, x_qs);
  hist_kernel<<<(EE + 255) / 256, 256, 0, stream>>>(e_src, deg);
  scanA_kernel<<<SNB, 256, 0, stream>>>(deg, Psum);
  scanB_kernel<<<1, 256, 0, stream>>>(Psum, Poff);
  scanC_kernel<<<SNB, 256, 0, stream>>>(deg, Poff, offs, cursor);
  scatter_kernel<<<(EE + 255) / 256, 256, 0, stream>>>(e_src, e_snk, dist, cursor, ssink, sdist);

  const int gM = NP / 64;  // 782

  for (int t = 0; t < TT; t++) {
    if (t == 0)
      gather_kernel<true><<<(NN + 3) / 4, 256, 0, stream>>>(
          offs, ssink, sdist, x_qs, mh);
    else
      gather_kernel<false><<<(NN + 3) / 4, 256, 0, stream>>>(
          offs, ssink, sdist, x_qs + (size_t)t * NN * ED, mh);
    colstats_s16_kernel<96><<<NPB2, 256, 0, stream>>>(mh, P);
    bnfinal2_kernel<<<256, 256, 0, stream>>>(P, NPB2, up_bn_g + t * MD, up_bn_b + t * MD, MD,
                                             na, nb);
    wscale_kernel<<<208, 256, 0, stream>>>(up_w1 + (size_t)t * MD * HH, na, nb,
                                           up_b1 + t * HH, MD, 96, w1sp, b1c);
    fused_kernel<false><<<gM, 512, 0, stream>>>(
        mh, 96, w1sp, 3,
        w2p + (size_t)t * 13 * 7 * 1024, w3p + (size_t)t * 13 * 7 * 1024,
        w4p + (size_t)t * 4 * 7 * 1024,
        b1c, up_b2 + t * HH, up_b3 + t * HH, up_b4 + t * ED,
        x_p, x_q, x_qs, t, nullptr, nullptr, nullptr);
  }

  colstats_s16_kernel<256><<<NPB2, 256, 0, stream>>>(x_q, P);
  bnfinal2_kernel<<<256, 256, 0, stream>>>(P, NPB2, ro_bn_g, ro_bn_b, RD, na, nb);
  wscale_kernel<<<208, 256, 0, stream>>>(ro_w1, na, nb, ro_b1, RD, 256, r1sp, b1c);
  fused_kernel<true><<<gM, 512, 0, stream>>>(
      x_q, 256, r1sp, 8,
      r2p, r3p, nullptr,
      b1c, ro_b2, ro_b3, ro_b4,
      nullptr, nullptr, nullptr, 0, ro_w4, mol, out);

  (void)in_sizes; (void)n_in; (void)out_size; (void)ws_size;
}